// Round 3
// baseline (2861.339 us; speedup 1.0000x reference)
//
#include <hip/hip_runtime.h>

#define N_NODES 50000
#define E_EDGES 800000
#define NG 16
#define DD 64
#define HH 128
#define NB_SCAN 49

typedef __attribute__((ext_vector_type(8))) __bf16 bf16x8;
typedef __attribute__((ext_vector_type(4))) float f32x4;
typedef unsigned int uint;
typedef unsigned short ushort;
typedef __attribute__((ext_vector_type(4))) uint uint4v;

#define MFMA16(a,b,c) __builtin_amdgcn_mfma_f32_16x16x32_bf16((a),(b),(c),0,0,0)

__device__ __forceinline__ ushort f2bf(float f){
  uint u = __builtin_bit_cast(uint, f);
  u += 0x7fffu + ((u >> 16) & 1u);
  return (ushort)(u >> 16);
}
__device__ __forceinline__ uint pk2(float a, float b){
  return (uint)f2bf(a) | ((uint)f2bf(b) << 16);
}
__device__ __forceinline__ float bflo(uint u){ return __builtin_bit_cast(float, u << 16); }
__device__ __forceinline__ float bfhi(uint u){ return __builtin_bit_cast(float, u & 0xffff0000u); }

// ---- pitch-256B LDS tile helpers (sH, node kernel tiles) ----
__device__ __forceinline__ bf16x8 ldfrag(const char* base, int row, int byteoff){
  uint4v v = *(const uint4v*)(base + row*256 + (byteoff ^ ((row & 7) << 4)));
  return __builtin_bit_cast(bf16x8, v);
}
__device__ __forceinline__ uint4v ld_chunk(const char* base, int row, int c16){
  return *(const uint4v*)(base + row*256 + ((c16*16) ^ ((row & 7) << 4)));
}
__device__ __forceinline__ void st_h(char* base, int row, int col, float v){
  *(ushort*)(base + row*256 + ((col*2) ^ ((row & 7) << 4))) = f2bf(v);
}
__device__ __forceinline__ void st_chunk(char* base, int row, int c16, uint4v v){
  *(uint4v*)(base + row*256 + ((c16*16) ^ ((row & 7) << 4))) = v;
}
__device__ __forceinline__ void pack16(char* dst, int r, int c16, const float* src){
  float4 lo = *(const float4*)src;
  float4 hi = *(const float4*)(src + 4);
  uint4v v; v.x = pk2(lo.x, lo.y); v.y = pk2(lo.z, lo.w);
  v.z = pk2(hi.x, hi.y); v.w = pk2(hi.z, hi.w);
  st_chunk(dst, r, c16, v);
}

// ---- pitch-512B LDS tile helpers (edge kernel sA: 64 rows x 256 bf16) ----
__device__ __forceinline__ bf16x8 ldfrag512(const char* base, int row, int byteoff){
  uint4v v = *(const uint4v*)(base + row*512 + (byteoff ^ ((row & 7) << 4)));
  return __builtin_bit_cast(bf16x8, v);
}
__device__ __forceinline__ uint4v ld_chunk512(const char* base, int row, int c16){
  return *(const uint4v*)(base + row*512 + ((c16*16) ^ ((row & 7) << 4)));
}
__device__ __forceinline__ void st_h512(char* base, int row, int col, float v){
  *(ushort*)(base + row*512 + ((col*2) ^ ((row & 7) << 4))) = f2bf(v);
}
__device__ __forceinline__ void pack16_512(char* dst, int r, int c16, const float* src){
  float4 lo = *(const float4*)src;
  float4 hi = *(const float4*)(src + 4);
  uint4v v; v.x = pk2(lo.x, lo.y); v.y = pk2(lo.z, lo.w);
  v.z = pk2(hi.x, hi.y); v.w = pk2(hi.z, hi.w);
  *(uint4v*)(dst + r*512 + ((c16*16) ^ ((r & 7) << 4))) = v;
}

// ---- reg-resident B fragments, loaded straight from global (L2-hit) ----
__device__ __forceinline__ void loadB16(bf16x8 (&b)[4][4], const ushort* wt, int K, int koff,
                                        int nbase, int l15, int lhi){
  #pragma unroll
  for (int kt = 0; kt < 4; ++kt)
    #pragma unroll
    for (int n = 0; n < 4; ++n)
      b[kt][n] = *(const bf16x8*)(wt + (long)((nbase + n)*16 + l15)*K + koff + kt*32 + lhi*8);
}
__device__ __forceinline__ void loadB8(bf16x8 (&b)[4][2], const ushort* wt, int K,
                                       int nbase, int l15, int lhi){
  #pragma unroll
  for (int kt = 0; kt < 4; ++kt)
    #pragma unroll
    for (int n = 0; n < 2; ++n)
      b[kt][n] = *(const bf16x8*)(wt + (long)((nbase + n)*16 + l15)*K + kt*32 + lhi*8);
}
__device__ __forceinline__ void gemmA512(const char* A, int abyte, bf16x8 (&b)[4][4],
                                         int mw, int l15, int lhi, f32x4* acc){
  #pragma unroll
  for (int kt = 0; kt < 4; ++kt){
    bf16x8 a = ldfrag512(A, mw*16 + l15, abyte + kt*64 + lhi*16);
    #pragma unroll
    for (int n = 0; n < 4; ++n) acc[n] = MFMA16(a, b[kt][n], acc[n]);
  }
}
__device__ __forceinline__ void gemmA256(const char* A, bf16x8 (&b)[4][4],
                                         int mw, int l15, int lhi, f32x4* acc){
  #pragma unroll
  for (int kt = 0; kt < 4; ++kt){
    bf16x8 a = ldfrag(A, mw*16 + l15, kt*64 + lhi*16);
    #pragma unroll
    for (int n = 0; n < 4; ++n) acc[n] = MFMA16(a, b[kt][n], acc[n]);
  }
}
// epi -> pitch-256 dst
template<bool RELU>
__device__ __forceinline__ void epiN4(char* dst, const f32x4* acc, const float* bias,
                                      int mw, int nh, int l15, int lhi){
  #pragma unroll
  for (int n = 0; n < 4; ++n){
    int col = nh*64 + n*16 + l15;
    float bv = bias[col];
    #pragma unroll
    for (int j = 0; j < 4; ++j){
      int r = mw*16 + lhi*4 + j;
      float v = acc[n][j] + bv;
      if (RELU) v = fmaxf(v, 0.f);
      st_h(dst, r, col, v);
    }
  }
}
// epi -> pitch-512 dst at column base
template<bool RELU>
__device__ __forceinline__ void epi512(char* dst, int colbase, const f32x4* acc, const float* bias,
                                       int mw, int nh, int l15, int lhi){
  #pragma unroll
  for (int n = 0; n < 4; ++n){
    int col = nh*64 + n*16 + l15;
    float bv = bias[col];
    #pragma unroll
    for (int j = 0; j < 4; ++j){
      int r = mw*16 + lhi*4 + j;
      float v = acc[n][j] + bv;
      if (RELU) v = fmaxf(v, 0.f);
      st_h512(dst, r, colbase + col, v);
    }
  }
}

// 4-wave helpers (node kernel)
__device__ __forceinline__ void stage_b(char* sB, const ushort* wt,
                                        int Nout, int Ktot, int koff, int t, int stride){
  for (int task = t; task < Nout*16; task += stride){
    int n = task >> 4, c = task & 15;
    uint4v v = *(const uint4v*)(wt + (long)n*Ktot + koff + c*8);
    st_chunk(sB, n, c, v);
  }
}
template<int NT>
__device__ __forceinline__ void gemm_acc(const char* A, const char* B,
                                         int wv, int l15, int lhi, f32x4* acc){
  #pragma unroll
  for (int kt = 0; kt < 4; ++kt){
    bf16x8 a = ldfrag(A, wv*16 + l15, kt*64 + lhi*16);
    #pragma unroll
    for (int n = 0; n < NT; ++n){
      bf16x8 bb = ldfrag(B, n*16 + l15, kt*64 + lhi*16);
      acc[n] = MFMA16(a, bb, acc[n]);
    }
  }
}
template<int NT, bool RELU>
__device__ __forceinline__ void epi_lds(char* dst, const f32x4* acc, const float* bias,
                                        int wv, int l15, int lhi){
  #pragma unroll
  for (int n = 0; n < NT; ++n){
    float bv = bias[n*16 + l15];
    #pragma unroll
    for (int j = 0; j < 4; ++j){
      int r = wv*16 + lhi*4 + j;
      float v = acc[n][j] + bv;
      if (RELU) v = fmaxf(v, 0.f);
      st_h(dst, r, n*16 + l15, v);
    }
  }
}

// ---------------- weight pack: fp32 [L][K][N] -> bf16 transposed [L][N][K] ----------
__global__ void pack_weights(const float* __restrict__ e1, const float* __restrict__ e2,
                             const float* __restrict__ e3, const float* __restrict__ n11,
                             const float* __restrict__ n12, const float* __restrict__ n21,
                             const float* __restrict__ n22, ushort* __restrict__ out){
  int idx = blockIdx.x * 256 + threadIdx.x;
  int l = idx / 131072, r = idx % 131072;
  const float* src; int K, N, off;
  if      (r <  32768){ src = e1;  K = 256; N = 128; off = 0; }
  else if (r <  49152){ src = e2;  K = 128; N = 128; off = 32768; }
  else if (r <  57344){ src = e3;  K = 128; N = 64;  off = 49152; }
  else if (r <  73728){ src = n11; K = 128; N = 128; off = 57344; }
  else if (r <  90112){ src = n12; K = 128; N = 128; off = 73728; }
  else if (r < 122880){ src = n21; K = 256; N = 128; off = 90112; }
  else                { src = n22; K = 128; N = 64;  off = 122880; }
  int q = r - off; int k = q / N; int n = q % N;
  out[(long)l*131072 + off + n*K + k] = f2bf(src[(long)l*K*N + q]);
}

// ---------------- counts / CSR ----------------
__global__ void hist_kernel(const int* __restrict__ edge_index, const int* __restrict__ batch,
                            int* __restrict__ deg, float* __restrict__ cnt_eb){
  __shared__ float h[NG];
  int t = threadIdx.x;
  if (t < NG) h[t] = 0.f;
  __syncthreads();
  int e = blockIdx.x * 256 + t;
  if (e < E_EDGES){
    atomicAdd(deg + edge_index[E_EDGES + e], 1);
    atomicAdd(&h[batch[edge_index[e]]], 1.f);
  }
  __syncthreads();
  if (t < NG) atomicAdd(cnt_eb + t, h[t]);
}
__global__ void count_nodes_kernel(const int* __restrict__ batch, float* __restrict__ cnt_b){
  __shared__ float h[NG];
  int t = threadIdx.x;
  if (t < NG) h[t] = 0.f;
  __syncthreads();
  int n = blockIdx.x * 256 + t;
  if (n < N_NODES) atomicAdd(&h[batch[n]], 1.f);
  __syncthreads();
  if (t < NG) atomicAdd(cnt_b + t, h[t]);
}
__global__ void scan_a(const int* __restrict__ deg, int* __restrict__ bsum){
  __shared__ int red[1024];
  int i = blockIdx.x*1024 + threadIdx.x;
  red[threadIdx.x] = (i < N_NODES) ? deg[i] : 0;
  __syncthreads();
  for (int s = 512; s > 0; s >>= 1){
    if ((int)threadIdx.x < s) red[threadIdx.x] += red[threadIdx.x + s];
    __syncthreads();
  }
  if (threadIdx.x == 0) bsum[blockIdx.x] = red[0];
}
__global__ void scan_b(const int* __restrict__ bsum, int* __restrict__ bbase){
  if (threadIdx.x == 0){
    int run = 0;
    for (int b = 0; b < NB_SCAN; ++b){ int v = bsum[b]; bbase[b] = run; run += v; }
  }
}
__global__ void scan_c(const int* __restrict__ deg, const int* __restrict__ bbase,
                       int* __restrict__ off, int* __restrict__ cursor){
  __shared__ int sc[1024];
  int i = blockIdx.x*1024 + threadIdx.x;
  int v = (i < N_NODES) ? deg[i] : 0;
  sc[threadIdx.x] = v;
  __syncthreads();
  for (int d = 1; d < 1024; d <<= 1){
    int add = ((int)threadIdx.x >= d) ? sc[threadIdx.x - d] : 0;
    __syncthreads();
    sc[threadIdx.x] += add;
    __syncthreads();
  }
  if (i < N_NODES){
    int ex = sc[threadIdx.x] - v + bbase[blockIdx.x];
    off[i] = ex; cursor[i] = ex;
  }
}
__global__ void fill_kernel(const int* __restrict__ edge_index, int* __restrict__ cursor,
                            int* __restrict__ pos){
  int e = blockIdx.x*256 + threadIdx.x;
  if (e < E_EDGES){
    int c = edge_index[E_EDGES + e];
    pos[e] = atomicAdd(&cursor[c], 1);
  }
}

// ---------------- edge kernel v3: reg-B, 7 barriers, region-reuse sA ----------------
template<bool CSR>
__global__ __launch_bounds__(512, 4) void edge_kernel(
    const float* __restrict__ x_cur, const float* __restrict__ e_cur,
    const float* __restrict__ u_cur, const float* __restrict__ e_resid,
    const int* __restrict__ edge_index, const int* __restrict__ batch,
    const int* __restrict__ pos_arr,
    const ushort* __restrict__ w_e1, const ushort* __restrict__ w_e2,
    const ushort* __restrict__ w_e3, const ushort* __restrict__ w_n11,
    const ushort* __restrict__ w_n12,
    const float* __restrict__ b_e1, const float* __restrict__ b_e2,
    const float* __restrict__ b_e3, const float* __restrict__ b_n11,
    const float* __restrict__ b_n12,
    float* __restrict__ e_out, ushort* __restrict__ se_buf,
    float* __restrict__ agg_sum, float* __restrict__ e_agg, int has_resid)
{
  __shared__ __align__(16) char sA[32768];   // 64 rows x 256 bf16 (pitch 512B)
  __shared__ __align__(16) char sH[16384];   // 64 rows x 128 bf16 (pitch 256B)
  __shared__ int sRow[64], sCol[64], sEb[64];
  __shared__ float sEagg[NG*DD];

  const int t = threadIdx.x;                 // 0..511
  const int wv = t >> 6, ln = t & 63, l15 = ln & 15, lhi = ln >> 4;
  const int mw = wv & 3, nh = wv >> 2;
  const int ebase = blockIdx.x * 64;

  if (t < 64){
    int r = edge_index[ebase + t];
    sRow[t] = r; sCol[t] = edge_index[E_EDGES + ebase + t]; sEb[t] = batch[r];
  }
  for (int i = t; i < NG*DD; i += 512) sEagg[i] = 0.f;
  __syncthreads();   // sRow/sCol/sEb visible for staging

  // ---- phase 0: stage full A (cols: 0-63 x_row, 64-127 x_col, 128-191 e, 192-255 u) ----
  #pragma unroll
  for (int it = 0; it < 4; ++it){
    int task = t + it*512;                   // 0..2047
    int r = task >> 5, c = task & 31;
    const float* src;
    if      (c <  8) src = x_cur + (long)sRow[r]*DD + c*8;
    else if (c < 16) src = x_cur + (long)sCol[r]*DD + (c-8)*8;
    else if (c < 24) src = e_cur + (long)(ebase + r)*DD + (c-16)*8;
    else             src = u_cur + (long)sEb[r]*DD + (c-24)*8;
    pack16_512(sA, r, c, src);
  }
  bf16x8 b[4][4];
  loadB16(b, w_e1, 256, 0, nh*4, l15, lhi);
  __syncthreads();                           // bar1

  // ---- GEMM1: K=256 in two reg-B halves ----
  f32x4 acc[4];
  #pragma unroll
  for (int n = 0; n < 4; ++n) acc[n] = f32x4{0.f,0.f,0.f,0.f};
  gemmA512(sA, 0, b, mw, l15, lhi, acc);
  loadB16(b, w_e1, 256, 128, nh*4, l15, lhi);
  gemmA512(sA, 256, b, mw, l15, lhi, acc);
  epiN4<true>(sH, acc, b_e1, mw, nh, l15, lhi);
  loadB16(b, w_e2, 128, 0, nh*4, l15, lhi);
  __syncthreads();                           // bar2

  // ---- GEMM2: H1(sH) -> H2 (sA cols 128-255) ----
  #pragma unroll
  for (int n = 0; n < 4; ++n) acc[n] = f32x4{0.f,0.f,0.f,0.f};
  gemmA256(sH, b, mw, l15, lhi, acc);
  epi512<true>(sA, 128, acc, b_e2, mw, nh, l15, lhi);
  bf16x8 b3[4][2];
  loadB8(b3, w_e3, 128, nh*2, l15, lhi);
  __syncthreads();                           // bar3

  // ---- GEMM3: H2 (sA cols 128-255) -> e_new; write e_out + sA cols 64-127 ----
  f32x4 acc3[2];
  acc3[0] = f32x4{0.f,0.f,0.f,0.f}; acc3[1] = f32x4{0.f,0.f,0.f,0.f};
  #pragma unroll
  for (int kt = 0; kt < 4; ++kt){
    bf16x8 a = ldfrag512(sA, mw*16 + l15, 256 + kt*64 + lhi*16);
    #pragma unroll
    for (int n = 0; n < 2; ++n) acc3[n] = MFMA16(a, b3[kt][n], acc3[n]);
  }
  #pragma unroll
  for (int n = 0; n < 2; ++n){
    int col = nh*32 + n*16 + l15;
    float bv = b_e3[col];
    #pragma unroll
    for (int j = 0; j < 4; ++j){
      int r = mw*16 + lhi*4 + j;
      float v = acc3[n][j] + bv;
      long eg = (long)(ebase + r)*DD + col;
      e_out[eg] = has_resid ? (v + e_resid[eg]) : v;
      atomicAdd(&sEagg[sEb[r]*DD + col], v);
      st_h512(sA, r, 64 + col, v);           // e_new into cols 64-127; x_row (0-63) intact
    }
  }
  loadB16(b, w_n11, 128, 0, nh*4, l15, lhi);
  __syncthreads();                           // bar4

  // ---- GEMM4: [x_row | e_new] (sA cols 0-127) -> H3 (sH) ----
  #pragma unroll
  for (int n = 0; n < 4; ++n) acc[n] = f32x4{0.f,0.f,0.f,0.f};
  gemmA512(sA, 0, b, mw, l15, lhi, acc);
  epiN4<true>(sH, acc, b_n11, mw, nh, l15, lhi);
  loadB16(b, w_n12, 128, 0, nh*4, l15, lhi);
  __syncthreads();                           // bar5

  // ---- GEMM5: H3 -> SE ----
  #pragma unroll
  for (int n = 0; n < 4; ++n) acc[n] = f32x4{0.f,0.f,0.f,0.f};
  gemmA256(sH, b, mw, l15, lhi, acc);

  if (CSR){
    epi512<false>(sA, 0, acc, b_n12, mw, nh, l15, lhi);
    __syncthreads();                         // bar6
    int r = t >> 3, oct = t & 7;
    long p = pos_arr[ebase + r];
    uint4v v0 = ld_chunk512(sA, r, oct*2);
    uint4v v1 = ld_chunk512(sA, r, oct*2 + 1);
    *(uint4v*)(se_buf + p*128 + oct*16) = v0;
    *(uint4v*)(se_buf + p*128 + oct*16 + 8) = v1;
  } else {
    #pragma unroll
    for (int n = 0; n < 4; ++n){
      int col = nh*64 + n*16 + l15;
      float bv = b_n12[col];
      #pragma unroll
      for (int j = 0; j < 4; ++j){
        int r = mw*16 + lhi*4 + j;
        atomicAdd(agg_sum + (long)sCol[r]*HH + col, acc[n][j] + bv);
      }
    }
    __syncthreads();
  }
  for (int i = t; i < NG*DD; i += 512) atomicAdd(e_agg + i, sEagg[i]);
}

// ---------------- node kernel: mean-gather + node-MLP2 (unchanged) ----------------
template<bool CSR>
__global__ __launch_bounds__(256, 2) void node_kernel(
    const float* __restrict__ x_cur, const float* __restrict__ u_cur,
    const float* __restrict__ x_resid, const int* __restrict__ batch,
    const ushort* __restrict__ se_buf, const int* __restrict__ deg,
    const int* __restrict__ off, const float* __restrict__ agg_sum,
    const ushort* __restrict__ w_n21, const ushort* __restrict__ w_n22,
    const float* __restrict__ b_n21, const float* __restrict__ b_n22,
    float* __restrict__ x_out, float* __restrict__ n_agg, int has_resid)
{
  __shared__ __align__(16) char sA[16384];
  __shared__ __align__(16) char sB[32768];
  __shared__ __align__(16) char sH[16384];
  __shared__ int sBat[64], sDeg[64], sOff[64];
  __shared__ float sRinv[64];
  __shared__ float sNagg[NG*DD];

  const int t = threadIdx.x;
  const int wv = t >> 6, ln = t & 63, l15 = ln & 15, lhi = ln >> 4;
  const int n0 = blockIdx.x * 64;

  if (t < 64){
    int nd = n0 + t;
    int ok = nd < N_NODES;
    sBat[t] = ok ? batch[nd] : 0;
    int d = ok ? deg[nd] : 0;
    sDeg[t] = d;
    sOff[t] = ok ? off[nd] : 0;
    sRinv[t] = 1.f / fmaxf((float)d, 1.f);
  }
  for (int i = t; i < NG*DD; i += 256) sNagg[i] = 0.f;
  __syncthreads();

  float s[32];
  const int r4 = t >> 2, q = t & 3;
  if (CSR){
    #pragma unroll
    for (int k = 0; k < 32; ++k) s[k] = 0.f;
    int d = sDeg[r4], o = sOff[r4];
    for (int i = 0; i < d; ++i){
      const ushort* src = se_buf + (long)(o + i)*HH + q*32;
      #pragma unroll
      for (int c = 0; c < 4; ++c){
        uint4v v = *(const uint4v*)(src + c*8);
        #pragma unroll
        for (int jj = 0; jj < 4; ++jj){
          s[c*8 + jj*2]     += bflo(v[jj]);
          s[c*8 + jj*2 + 1] += bfhi(v[jj]);
        }
      }
    }
    float riv = sRinv[r4];
    #pragma unroll
    for (int k = 0; k < 32; ++k) s[k] *= riv;
  }

  f32x4 acc[8];
  #pragma unroll
  for (int n = 0; n < 8; ++n) acc[n] = f32x4{0.f,0.f,0.f,0.f};

  for (int half = 0; half < 2; ++half){
    if (CSR){
      for (int task = t; task < 512; task += 256){
        int r = task >> 3, c = task & 7;
        int nd = n0 + r;
        bool ok = nd < N_NODES;
        float4 lo = {0,0,0,0}, hi = {0,0,0,0};
        if (ok){
          const float* src = (half == 0) ? (x_cur + (long)nd*DD + c*8)
                                         : (u_cur + (long)sBat[r]*DD + c*8);
          lo = *(const float4*)src; hi = *(const float4*)(src + 4);
        }
        uint4v v; v.x = pk2(lo.x, lo.y); v.y = pk2(lo.z, lo.w);
        v.z = pk2(hi.x, hi.y); v.w = pk2(hi.z, hi.w);
        st_chunk(sA, r, (half == 0) ? c : (8 + c), v);
      }
      if ((half == 0 && q < 2) || (half == 1 && q >= 2)){
        int cbase = (half == 0) ? (8 + q*4) : ((q - 2)*4);
        #pragma unroll
        for (int cc = 0; cc < 4; ++cc){
          uint4v v;
          v.x = pk2(s[cc*8+0], s[cc*8+1]); v.y = pk2(s[cc*8+2], s[cc*8+3]);
          v.z = pk2(s[cc*8+4], s[cc*8+5]); v.w = pk2(s[cc*8+6], s[cc*8+7]);
          st_chunk(sA, r4, cbase + cc, v);
        }
      }
    } else {
      for (int task = t; task < 1024; task += 256){
        int r = task >> 4, c = task & 15;
        int nd = n0 + r;
        bool ok = nd < N_NODES;
        float scale = 1.f;
        const float* src;
        if (half == 0){
          if (c < 8) src = x_cur + (long)nd*DD + c*8;
          else { src = agg_sum + (long)nd*HH + (c-8)*8; scale = sRinv[r]; }
        } else {
          if (c < 8){ src = agg_sum + (long)nd*HH + 64 + c*8; scale = sRinv[r]; }
          else src = u_cur + (long)sBat[r]*DD + (c-8)*8;
        }
        float4 lo = {0,0,0,0}, hi = {0,0,0,0};
        if (ok){ lo = *(const float4*)src; hi = *(const float4*)(src + 4); }
        uint4v v; v.x = pk2(lo.x*scale, lo.y*scale); v.y = pk2(lo.z*scale, lo.w*scale);
        v.z = pk2(hi.x*scale, hi.y*scale); v.w = pk2(hi.z*scale, hi.w*scale);
        st_chunk(sA, r, c, v);
      }
    }
    stage_b(sB, w_n21, 128, 256, half*128, t, 256);
    __syncthreads();
    gemm_acc<8>(sA, sB, wv, l15, lhi, acc);
    __syncthreads();
  }
  epi_lds<8, true>(sH, acc, b_n21, wv, l15, lhi);
  stage_b(sB, w_n22, 64, 128, 0, t, 256);
  __syncthreads();

  f32x4 acc2[4];
  #pragma unroll
  for (int n = 0; n < 4; ++n) acc2[n] = f32x4{0.f,0.f,0.f,0.f};
  gemm_acc<4>(sH, sB, wv, l15, lhi, acc2);

  #pragma unroll
  for (int n = 0; n < 4; ++n){
    float bv = b_n22[n*16 + l15];
    #pragma unroll
    for (int j = 0; j < 4; ++j){
      int r = wv*16 + lhi*4 + j;
      int nd = n0 + r;
      if (nd < N_NODES){
        int col = n*16 + l15;
        float v = acc2[n][j] + bv;
        long xg = (long)nd*DD + col;
        x_out[xg] = has_resid ? (v + x_resid[xg]) : v;
        atomicAdd(&sNagg[sBat[r]*DD + col], v);
      }
    }
  }
  __syncthreads();
  for (int i = t; i < NG*DD; i += 256) atomicAdd(n_agg + i, sNagg[i]);
}

// ---------------- global (per-graph) MLP, fp32 ----------------
__global__ void global_kernel(const float* __restrict__ u_cur, const float* __restrict__ n_agg,
                              const float* __restrict__ e_agg, const float* __restrict__ cnt_b,
                              const float* __restrict__ cnt_e,
                              const float* __restrict__ g_w1, const float* __restrict__ g_b1,
                              const float* __restrict__ g_w2, const float* __restrict__ g_b2,
                              const float* __restrict__ u_resid, float* __restrict__ u_out,
                              int has_resid)
{
  int g = blockIdx.x, t = threadIdx.x;   // 192 threads
  __shared__ float uh[192];
  __shared__ float hb[128];
  float v;
  if (t < 64)       v = u_cur[g*64 + t];
  else if (t < 128) v = n_agg[g*64 + (t-64)] / fmaxf(cnt_b[g], 1.f);
  else              v = e_agg[g*64 + (t-128)] / fmaxf(cnt_e[g], 1.f);
  uh[t] = v;
  __syncthreads();
  if (t < 128){
    float s = g_b1[t];
    for (int k = 0; k < 192; ++k) s += uh[k] * g_w1[k*128 + t];
    hb[t] = fmaxf(s, 0.f);
  }
  __syncthreads();
  if (t < 64){
    float s = g_b2[t];
    for (int k = 0; k < 128; ++k) s += hb[k] * g_w2[k*64 + t];
    if (has_resid) s += u_resid[g*64 + t];
    u_out[g*64 + t] = s;
  }
}

extern "C" void kernel_launch(void* const* d_in, const int* in_sizes, int n_in,
                              void* d_out, int out_size, void* d_ws, size_t ws_size,
                              hipStream_t stream)
{
  const float* x0   = (const float*)d_in[0];
  const float* e0   = (const float*)d_in[1];
  const float* u0   = (const float*)d_in[2];
  const float* e_w1 = (const float*)d_in[3];
  const float* e_b1 = (const float*)d_in[4];
  const float* e_w2 = (const float*)d_in[5];
  const float* e_b2 = (const float*)d_in[6];
  const float* e_w3 = (const float*)d_in[7];
  const float* e_b3 = (const float*)d_in[8];
  const float* n1_w1 = (const float*)d_in[9];
  const float* n1_b1 = (const float*)d_in[10];
  const float* n1_w2 = (const float*)d_in[11];
  const float* n1_b2 = (const float*)d_in[12];
  const float* n2_w1 = (const float*)d_in[13];
  const float* n2_b1 = (const float*)d_in[14];
  const float* n2_w2 = (const float*)d_in[15];
  const float* n2_b2 = (const float*)d_in[16];
  const float* g_w1 = (const float*)d_in[17];
  const float* g_b1 = (const float*)d_in[18];
  const float* g_w2 = (const float*)d_in[19];
  const float* g_b2 = (const float*)d_in[20];
  const int* edge_index = (const int*)d_in[21];
  const int* batch      = (const int*)d_in[22];

  float* out_x = (float*)d_out;
  float* out_e = out_x + (long)N_NODES*DD;
  float* out_u = out_e + (long)E_EDGES*DD;

  char* ws = (char*)d_ws;
  int*   deg    = (int*)(ws + 0);            // 200,000
  int*   off    = (int*)(ws + 200000);       // 200,000
  int*   cursor = (int*)(ws + 400000);       // 200,000
  int*   bsum   = (int*)(ws + 600000);       // 256
  int*   bbase  = (int*)(ws + 600256);       // 256
  float* cnt_eb = (float*)(ws + 600512);     // 64
  float* cnt_b  = (float*)(ws + 600576);     // 64
  float* e_agg  = (float*)(ws + 600640);     // 4096
  float* n_agg  = (float*)(ws + 604736);     // 4096
  ushort* packed = (ushort*)(ws + 608832);   // 524,288 -> ends 1,133,120
  const size_t big = 1133120;
  bool use_csr = ws_size >= (size_t)(big + 204800000 + 3200000);
  ushort* se_buf = (ushort*)(ws + big);
  int*    pos    = (int*)(ws + big + 204800000);
  float*  agg_sum = (float*)(ws + big);      // fallback overlay (25.6 MB)

  (void)hipMemsetAsync(deg, 0, 200000, stream);
  (void)hipMemsetAsync(cnt_eb, 0, 128, stream);
  pack_weights<<<1024, 256, 0, stream>>>(e_w1, e_w2, e_w3, n1_w1, n1_w2, n2_w1, n2_w2, packed);
  hist_kernel<<<3125, 256, 0, stream>>>(edge_index, batch, deg, cnt_eb);
  count_nodes_kernel<<<196, 256, 0, stream>>>(batch, cnt_b);
  if (use_csr){
    scan_a<<<NB_SCAN, 1024, 0, stream>>>(deg, bsum);
    scan_b<<<1, 64, 0, stream>>>(bsum, bbase);
    scan_c<<<NB_SCAN, 1024, 0, stream>>>(deg, bbase, off, cursor);
    fill_kernel<<<3125, 256, 0, stream>>>(edge_index, cursor, pos);
  }

  const float* xc = x0;
  const float* ec = e0;
  const float* uc = u0;
  for (int l = 0; l < 2; ++l){
    (void)hipMemsetAsync(e_agg, 0, 8192, stream);   // e_agg + n_agg
    if (!use_csr)
      (void)hipMemsetAsync(agg_sum, 0, (size_t)N_NODES*HH*4, stream);
    const ushort* P = packed + (long)l*131072;
    if (use_csr){
      edge_kernel<true><<<E_EDGES/64, 512, 0, stream>>>(
          xc, ec, uc, e0, edge_index, batch, pos,
          P + 0, P + 32768, P + 49152, P + 57344, P + 73728,
          e_b1 + l*128, e_b2 + l*128, e_b3 + l*64, n1_b1 + l*128, n1_b2 + l*128,
          out_e, se_buf, agg_sum, e_agg, l == 1);
      node_kernel<true><<<782, 256, 0, stream>>>(
          xc, uc, x0, batch, se_buf, deg, off, agg_sum,
          P + 90112, P + 122880, n2_b1 + l*128, n2_b2 + l*64,
          out_x, n_agg, l == 1);
    } else {
      edge_kernel<false><<<E_EDGES/64, 512, 0, stream>>>(
          xc, ec, uc, e0, edge_index, batch, pos,
          P + 0, P + 32768, P + 49152, P + 57344, P + 73728,
          e_b1 + l*128, e_b2 + l*128, e_b3 + l*64, n1_b1 + l*128, n1_b2 + l*128,
          out_e, se_buf, agg_sum, e_agg, l == 1);
      node_kernel<false><<<782, 256, 0, stream>>>(
          xc, uc, x0, batch, se_buf, deg, off, agg_sum,
          P + 90112, P + 122880, n2_b1 + l*128, n2_b2 + l*64,
          out_x, n_agg, l == 1);
    }
    global_kernel<<<NG, 192, 0, stream>>>(
        uc, n_agg, e_agg, cnt_b, cnt_eb,
        g_w1 + l*192*128, g_b1 + l*128, g_w2 + l*128*64, g_b2 + l*64,
        u0, out_u, l == 1);
    xc = out_x; ec = out_e; uc = out_u;
  }
}

// Round 4
// 2582.718 us; speedup vs baseline: 1.1079x; 1.1079x over previous
//
#include <hip/hip_runtime.h>

#define N_NODES 50000
#define E_EDGES 800000
#define NG 16
#define DD 64
#define HH 128
#define NB_SCAN 49
#define NTILES 12500

typedef __attribute__((ext_vector_type(8))) __bf16 bf16x8;
typedef __attribute__((ext_vector_type(4))) float f32x4;
typedef unsigned int uint;
typedef unsigned short ushort;
typedef __attribute__((ext_vector_type(4))) uint uint4v;

#define MFMA16(a,b,c) __builtin_amdgcn_mfma_f32_16x16x32_bf16((a),(b),(c),0,0,0)

__device__ __forceinline__ ushort f2bf(float f){
  uint u = __builtin_bit_cast(uint, f);
  u += 0x7fffu + ((u >> 16) & 1u);
  return (ushort)(u >> 16);
}
__device__ __forceinline__ uint pk2(float a, float b){
  return (uint)f2bf(a) | ((uint)f2bf(b) << 16);
}
__device__ __forceinline__ float bflo(uint u){ return __builtin_bit_cast(float, u << 16); }
__device__ __forceinline__ float bfhi(uint u){ return __builtin_bit_cast(float, u & 0xffff0000u); }

// ---- pitch-256B LDS helpers ----
__device__ __forceinline__ bf16x8 ldfrag(const char* base, int row, int byteoff){
  uint4v v = *(const uint4v*)(base + row*256 + (byteoff ^ ((row & 7) << 4)));
  return __builtin_bit_cast(bf16x8, v);
}
__device__ __forceinline__ void st_h(char* base, int row, int col, float v){
  *(ushort*)(base + row*256 + ((col*2) ^ ((row & 7) << 4))) = f2bf(v);
}
__device__ __forceinline__ void st_chunk(char* base, int row, int c16, uint4v v){
  *(uint4v*)(base + row*256 + ((c16*16) ^ ((row & 7) << 4))) = v;
}
__device__ __forceinline__ void pack16(char* dst, int r, int c16, const float* src){
  float4 lo = *(const float4*)src;
  float4 hi = *(const float4*)(src + 4);
  uint4v v; v.x = pk2(lo.x, lo.y); v.y = pk2(lo.z, lo.w);
  v.z = pk2(hi.x, hi.y); v.w = pk2(hi.z, hi.w);
  st_chunk(dst, r, c16, v);
}
// ---- pitch-512B LDS helpers (edge sA: 64 x 256 bf16) ----
__device__ __forceinline__ bf16x8 ldfrag512(const char* base, int row, int byteoff){
  uint4v v = *(const uint4v*)(base + row*512 + (byteoff ^ ((row & 7) << 4)));
  return __builtin_bit_cast(bf16x8, v);
}
__device__ __forceinline__ uint4v ld_chunk512(const char* base, int row, int c16){
  return *(const uint4v*)(base + row*512 + ((c16*16) ^ ((row & 7) << 4)));
}
__device__ __forceinline__ void st_h512(char* base, int row, int col, float v){
  *(ushort*)(base + row*512 + ((col*2) ^ ((row & 7) << 4))) = f2bf(v);
}
__device__ __forceinline__ void pack16_512(char* dst, int r, int c16, const float* src){
  float4 lo = *(const float4*)src;
  float4 hi = *(const float4*)(src + 4);
  uint4v v; v.x = pk2(lo.x, lo.y); v.y = pk2(lo.z, lo.w);
  v.z = pk2(hi.x, hi.y); v.w = pk2(hi.z, hi.w);
  *(uint4v*)(dst + r*512 + ((c16*16) ^ ((r & 7) << 4))) = v;
}

// persistent reg-B loader: wt is [N][K] bf16; wave owns n-frags {nbase, nbase+1}
template<int KT>
__device__ __forceinline__ void loadBreg(bf16x8 (&b)[KT][2], const ushort* wt, int K,
                                         int nbase, int l15, int lhi){
  #pragma unroll
  for (int kt = 0; kt < KT; ++kt)
    #pragma unroll
    for (int n = 0; n < 2; ++n)
      b[kt][n] = *(const bf16x8*)(wt + (long)((nbase + n)*16 + l15)*K + kt*32 + lhi*8);
}

// 4-wave helpers (node kernel, unchanged)
__device__ __forceinline__ void stage_b(char* sB, const ushort* wt,
                                        int Nout, int Ktot, int koff, int t, int stride){
  for (int task = t; task < Nout*16; task += stride){
    int n = task >> 4, c = task & 15;
    uint4v v = *(const uint4v*)(wt + (long)n*Ktot + koff + c*8);
    st_chunk(sB, n, c, v);
  }
}
template<int NT>
__device__ __forceinline__ void gemm_acc(const char* A, const char* B,
                                         int wv, int l15, int lhi, f32x4* acc){
  #pragma unroll
  for (int kt = 0; kt < 4; ++kt){
    bf16x8 a = ldfrag(A, wv*16 + l15, kt*64 + lhi*16);
    #pragma unroll
    for (int n = 0; n < NT; ++n){
      bf16x8 bb = ldfrag(B, n*16 + l15, kt*64 + lhi*16);
      acc[n] = MFMA16(a, bb, acc[n]);
    }
  }
}
template<int NT, bool RELU>
__device__ __forceinline__ void epi_lds(char* dst, const f32x4* acc, const float* bias,
                                        int wv, int l15, int lhi){
  #pragma unroll
  for (int n = 0; n < NT; ++n){
    float bv = bias[n*16 + l15];
    #pragma unroll
    for (int j = 0; j < 4; ++j){
      int r = wv*16 + lhi*4 + j;
      float v = acc[n][j] + bv;
      if (RELU) v = fmaxf(v, 0.f);
      st_h(dst, r, n*16 + l15, v);
    }
  }
}

// ---------------- weight pack: fp32 [L][K][N] -> bf16 transposed [L][N][K] ----------
__global__ void pack_weights(const float* __restrict__ e1, const float* __restrict__ e2,
                             const float* __restrict__ e3, const float* __restrict__ n11,
                             const float* __restrict__ n12, const float* __restrict__ n21,
                             const float* __restrict__ n22, ushort* __restrict__ out){
  int idx = blockIdx.x * 256 + threadIdx.x;
  int l = idx / 131072, r = idx % 131072;
  const float* src; int K, N, off;
  if      (r <  32768){ src = e1;  K = 256; N = 128; off = 0; }
  else if (r <  49152){ src = e2;  K = 128; N = 128; off = 32768; }
  else if (r <  57344){ src = e3;  K = 128; N = 64;  off = 49152; }
  else if (r <  73728){ src = n11; K = 128; N = 128; off = 57344; }
  else if (r <  90112){ src = n12; K = 128; N = 128; off = 73728; }
  else if (r < 122880){ src = n21; K = 256; N = 128; off = 90112; }
  else                { src = n22; K = 128; N = 64;  off = 122880; }
  int q = r - off; int k = q / N; int n = q % N;
  out[(long)l*131072 + off + n*K + k] = f2bf(src[(long)l*K*N + q]);
}

// ---------------- counts / CSR ----------------
__global__ void hist_kernel(const int* __restrict__ edge_index, const int* __restrict__ batch,
                            int* __restrict__ deg, float* __restrict__ cnt_eb){
  __shared__ float h[NG];
  int t = threadIdx.x;
  if (t < NG) h[t] = 0.f;
  __syncthreads();
  int e = blockIdx.x * 256 + t;
  if (e < E_EDGES){
    atomicAdd(deg + edge_index[E_EDGES + e], 1);
    atomicAdd(&h[batch[edge_index[e]]], 1.f);
  }
  __syncthreads();
  if (t < NG) atomicAdd(cnt_eb + t, h[t]);
}
__global__ void count_nodes_kernel(const int* __restrict__ batch, float* __restrict__ cnt_b){
  __shared__ float h[NG];
  int t = threadIdx.x;
  if (t < NG) h[t] = 0.f;
  __syncthreads();
  int n = blockIdx.x * 256 + t;
  if (n < N_NODES) atomicAdd(&h[batch[n]], 1.f);
  __syncthreads();
  if (t < NG) atomicAdd(cnt_b + t, h[t]);
}
__global__ void scan_a(const int* __restrict__ deg, int* __restrict__ bsum){
  __shared__ int red[1024];
  int i = blockIdx.x*1024 + threadIdx.x;
  red[threadIdx.x] = (i < N_NODES) ? deg[i] : 0;
  __syncthreads();
  for (int s = 512; s > 0; s >>= 1){
    if ((int)threadIdx.x < s) red[threadIdx.x] += red[threadIdx.x + s];
    __syncthreads();
  }
  if (threadIdx.x == 0) bsum[blockIdx.x] = red[0];
}
__global__ void scan_b(const int* __restrict__ bsum, int* __restrict__ bbase){
  if (threadIdx.x == 0){
    int run = 0;
    for (int b = 0; b < NB_SCAN; ++b){ int v = bsum[b]; bbase[b] = run; run += v; }
  }
}
__global__ void scan_c(const int* __restrict__ deg, const int* __restrict__ bbase,
                       int* __restrict__ off, int* __restrict__ cursor){
  __shared__ int sc[1024];
  int i = blockIdx.x*1024 + threadIdx.x;
  int v = (i < N_NODES) ? deg[i] : 0;
  sc[threadIdx.x] = v;
  __syncthreads();
  for (int d = 1; d < 1024; d <<= 1){
    int add = ((int)threadIdx.x >= d) ? sc[threadIdx.x - d] : 0;
    __syncthreads();
    sc[threadIdx.x] += add;
    __syncthreads();
  }
  if (i < N_NODES){
    int ex = sc[threadIdx.x] - v + bbase[blockIdx.x];
    off[i] = ex; cursor[i] = ex;
  }
}
__global__ void fill_kernel(const int* __restrict__ edge_index, int* __restrict__ cursor,
                            int* __restrict__ pos){
  int e = blockIdx.x*256 + threadIdx.x;
  if (e < E_EDGES){
    int c = edge_index[E_EDGES + e];
    pos[e] = atomicAdd(&cursor[c], 1);
  }
}

// ------------- edge kernel v4: persistent blocks, reg-B weights, tile loop -------------
// 8 waves: mw = wv&1 (rows mw*32, 2 m-frags), ng = wv>>1 (cols ng*32, 2 n-frags)
template<bool CSR>
__global__ __launch_bounds__(512, 2) void edge_kernel(
    const float* __restrict__ x_cur, const float* __restrict__ e_cur,
    const float* __restrict__ u_cur, const float* __restrict__ e_resid,
    const int* __restrict__ edge_index, const int* __restrict__ batch,
    const int* __restrict__ pos_arr,
    const ushort* __restrict__ w_e1, const ushort* __restrict__ w_e2,
    const ushort* __restrict__ w_e3, const ushort* __restrict__ w_n11,
    const ushort* __restrict__ w_n12,
    const float* __restrict__ b_e1, const float* __restrict__ b_e2,
    const float* __restrict__ b_e3, const float* __restrict__ b_n11,
    const float* __restrict__ b_n12,
    float* __restrict__ e_out, ushort* __restrict__ se_buf,
    float* __restrict__ agg_sum, float* __restrict__ e_agg, int has_resid)
{
  __shared__ __align__(16) char sA[32768];   // 64 x 256 bf16, pitch 512B
  __shared__ __align__(16) char sH[16384];   // 64 x 128 bf16, pitch 256B
  __shared__ __align__(16) char sW3[16384];  // e_w3: 64(N) x 128(K) bf16
  __shared__ int sRow[64], sCol[64], sEb[64];
  __shared__ float sEagg[NG*DD];

  const int t = threadIdx.x;
  const int wv = t >> 6, ln = t & 63, l15 = ln & 15, lhi = ln >> 4;
  const int mw = wv & 1, ng = wv >> 1;

  // one-time setup: weights into regs / sW3, eagg zero, first tile's indices
  bf16x8 b1[8][2], b2[4][2], b4[4][2], b5[4][2];
  loadBreg<8>(b1, w_e1, 256, ng*2, l15, lhi);
  loadBreg<4>(b2, w_e2, 128, ng*2, l15, lhi);
  loadBreg<4>(b4, w_n11, 128, ng*2, l15, lhi);
  loadBreg<4>(b5, w_n12, 128, ng*2, l15, lhi);
  #pragma unroll
  for (int it = 0; it < 2; ++it){
    int task = t + it*512;   // 1024 chunks of e_w3
    int n = task >> 4, c = task & 15;
    uint4v v = *(const uint4v*)(w_e3 + (long)n*128 + c*8);
    st_chunk(sW3, n, c, v);
  }
  for (int i = t; i < NG*DD; i += 512) sEagg[i] = 0.f;
  int tile = blockIdx.x;
  if (tile < NTILES && t < 64){
    int r = edge_index[tile*64 + t];
    sRow[t] = r; sCol[t] = edge_index[E_EDGES + tile*64 + t]; sEb[t] = batch[r];
  }

  for (; tile < NTILES; tile += gridDim.x){
    const int ebase = tile*64;
    __syncthreads();                          // bar0: indices visible, sA free

    // ---- stage A: cols 0-63 x_row | 64-127 x_col | 128-191 e | 192-255 u ----
    #pragma unroll
    for (int it = 0; it < 4; ++it){
      int task = t + it*512;
      int r = task >> 5, c = task & 31;
      const float* src;
      if      (c <  8) src = x_cur + (long)sRow[r]*DD + c*8;
      else if (c < 16) src = x_cur + (long)sCol[r]*DD + (c-8)*8;
      else if (c < 24) src = e_cur + (long)(ebase + r)*DD + (c-16)*8;
      else             src = u_cur + (long)sEb[r]*DD + (c-24)*8;
      pack16_512(sA, r, c, src);
    }
    __syncthreads();                          // bar1

    // ---- GEMM1: K=256 -> H1 (sH) ----
    f32x4 acc[2][2];
    #pragma unroll
    for (int m = 0; m < 2; ++m){ acc[m][0] = f32x4{0,0,0,0}; acc[m][1] = f32x4{0,0,0,0}; }
    #pragma unroll
    for (int kt = 0; kt < 8; ++kt){
      bf16x8 a0 = ldfrag512(sA, mw*32 + l15,      kt*64 + lhi*16);
      bf16x8 a1 = ldfrag512(sA, mw*32 + 16 + l15, kt*64 + lhi*16);
      acc[0][0] = MFMA16(a0, b1[kt][0], acc[0][0]);
      acc[0][1] = MFMA16(a0, b1[kt][1], acc[0][1]);
      acc[1][0] = MFMA16(a1, b1[kt][0], acc[1][0]);
      acc[1][1] = MFMA16(a1, b1[kt][1], acc[1][1]);
    }
    #pragma unroll
    for (int m = 0; m < 2; ++m)
      #pragma unroll
      for (int n = 0; n < 2; ++n){
        int col = ng*32 + n*16 + l15;
        float bv = b_e1[col];
        #pragma unroll
        for (int j = 0; j < 4; ++j)
          st_h(sH, mw*32 + m*16 + lhi*4 + j, col, fmaxf(acc[m][n][j] + bv, 0.f));
      }
    __syncthreads();                          // bar2

    // ---- GEMM2: H1 -> H2 (sA cols 128-255) ----
    #pragma unroll
    for (int m = 0; m < 2; ++m){ acc[m][0] = f32x4{0,0,0,0}; acc[m][1] = f32x4{0,0,0,0}; }
    #pragma unroll
    for (int kt = 0; kt < 4; ++kt){
      bf16x8 a0 = ldfrag(sH, mw*32 + l15,      kt*64 + lhi*16);
      bf16x8 a1 = ldfrag(sH, mw*32 + 16 + l15, kt*64 + lhi*16);
      acc[0][0] = MFMA16(a0, b2[kt][0], acc[0][0]);
      acc[0][1] = MFMA16(a0, b2[kt][1], acc[0][1]);
      acc[1][0] = MFMA16(a1, b2[kt][0], acc[1][0]);
      acc[1][1] = MFMA16(a1, b2[kt][1], acc[1][1]);
    }
    #pragma unroll
    for (int m = 0; m < 2; ++m)
      #pragma unroll
      for (int n = 0; n < 2; ++n){
        int col = ng*32 + n*16 + l15;
        float bv = b_e2[col];
        #pragma unroll
        for (int j = 0; j < 4; ++j)
          st_h512(sA, mw*32 + m*16 + lhi*4 + j, 128 + col, fmaxf(acc[m][n][j] + bv, 0.f));
      }
    __syncthreads();                          // bar3

    // ---- GEMM3: H2 -> e_new (N=64, B from sW3); write e_out, eagg, sA cols 64-127 ----
    {
      f32x4 a3[2];
      a3[0] = f32x4{0,0,0,0}; a3[1] = f32x4{0,0,0,0};
      #pragma unroll
      for (int kt = 0; kt < 4; ++kt){
        bf16x8 bb = ldfrag(sW3, ng*16 + l15, kt*64 + lhi*16);
        bf16x8 a0 = ldfrag512(sA, mw*32 + l15,      256 + kt*64 + lhi*16);
        bf16x8 a1 = ldfrag512(sA, mw*32 + 16 + l15, 256 + kt*64 + lhi*16);
        a3[0] = MFMA16(a0, bb, a3[0]);
        a3[1] = MFMA16(a1, bb, a3[1]);
      }
      int col = ng*16 + l15;
      float bv = b_e3[col];
      #pragma unroll
      for (int m = 0; m < 2; ++m)
        #pragma unroll
        for (int j = 0; j < 4; ++j){
          int r = mw*32 + m*16 + lhi*4 + j;
          float v = a3[m][j] + bv;
          long eg = (long)(ebase + r)*DD + col;
          e_out[eg] = has_resid ? (v + e_resid[eg]) : v;
          atomicAdd(&sEagg[sEb[r]*DD + col], v);
          st_h512(sA, r, 64 + col, v);
        }
    }
    __syncthreads();                          // bar4

    // ---- GEMM4: [x_row|e_new] (sA cols 0-127) -> H3 (sH) ----
    #pragma unroll
    for (int m = 0; m < 2; ++m){ acc[m][0] = f32x4{0,0,0,0}; acc[m][1] = f32x4{0,0,0,0}; }
    #pragma unroll
    for (int kt = 0; kt < 4; ++kt){
      bf16x8 a0 = ldfrag512(sA, mw*32 + l15,      kt*64 + lhi*16);
      bf16x8 a1 = ldfrag512(sA, mw*32 + 16 + l15, kt*64 + lhi*16);
      acc[0][0] = MFMA16(a0, b4[kt][0], acc[0][0]);
      acc[0][1] = MFMA16(a0, b4[kt][1], acc[0][1]);
      acc[1][0] = MFMA16(a1, b4[kt][0], acc[1][0]);
      acc[1][1] = MFMA16(a1, b4[kt][1], acc[1][1]);
    }
    #pragma unroll
    for (int m = 0; m < 2; ++m)
      #pragma unroll
      for (int n = 0; n < 2; ++n){
        int col = ng*32 + n*16 + l15;
        float bv = b_n11[col];
        #pragma unroll
        for (int j = 0; j < 4; ++j)
          st_h(sH, mw*32 + m*16 + lhi*4 + j, col, fmaxf(acc[m][n][j] + bv, 0.f));
      }
    __syncthreads();                          // bar5

    // ---- GEMM5: H3 -> SE ----
    #pragma unroll
    for (int m = 0; m < 2; ++m){ acc[m][0] = f32x4{0,0,0,0}; acc[m][1] = f32x4{0,0,0,0}; }
    #pragma unroll
    for (int kt = 0; kt < 4; ++kt){
      bf16x8 a0 = ldfrag(sH, mw*32 + l15,      kt*64 + lhi*16);
      bf16x8 a1 = ldfrag(sH, mw*32 + 16 + l15, kt*64 + lhi*16);
      acc[0][0] = MFMA16(a0, b5[kt][0], acc[0][0]);
      acc[0][1] = MFMA16(a0, b5[kt][1], acc[0][1]);
      acc[1][0] = MFMA16(a1, b5[kt][0], acc[1][0]);
      acc[1][1] = MFMA16(a1, b5[kt][1], acc[1][1]);
    }
    if (CSR){
      #pragma unroll
      for (int m = 0; m < 2; ++m)
        #pragma unroll
        for (int n = 0; n < 2; ++n){
          int col = ng*32 + n*16 + l15;
          float bv = b_n12[col];
          #pragma unroll
          for (int j = 0; j < 4; ++j)
            st_h512(sA, mw*32 + m*16 + lhi*4 + j, col, acc[m][n][j] + bv);
        }
      __syncthreads();                        // bar6
      {
        int r = t >> 3, oct = t & 7;
        long p = pos_arr[ebase + r];
        uint4v v0 = ld_chunk512(sA, r, oct*2);
        uint4v v1 = ld_chunk512(sA, r, oct*2 + 1);
        *(uint4v*)(se_buf + p*128 + oct*16) = v0;
        *(uint4v*)(se_buf + p*128 + oct*16 + 8) = v1;
      }
    } else {
      #pragma unroll
      for (int m = 0; m < 2; ++m)
        #pragma unroll
        for (int n = 0; n < 2; ++n){
          int col = ng*32 + n*16 + l15;
          float bv = b_n12[col];
          #pragma unroll
          for (int j = 0; j < 4; ++j)
            atomicAdd(agg_sum + (long)sCol[mw*32 + m*16 + lhi*4 + j]*HH + col,
                      acc[m][n][j] + bv);
        }
      __syncthreads();                        // bar6
    }
    // prefetch next tile's indices (sRow/sCol/sEb last read before bar4)
    int nt = tile + gridDim.x;
    if (nt < NTILES && t < 64){
      int r = edge_index[nt*64 + t];
      sRow[t] = r; sCol[t] = edge_index[E_EDGES + nt*64 + t]; sEb[t] = batch[r];
    }
  }
  __syncthreads();
  for (int i = t; i < NG*DD; i += 512) atomicAdd(e_agg + i, sEagg[i]);
}

// ---------------- node kernel: mean-gather + node-MLP2 (unchanged from R2) ----------------
template<bool CSR>
__global__ __launch_bounds__(256, 2) void node_kernel(
    const float* __restrict__ x_cur, const float* __restrict__ u_cur,
    const float* __restrict__ x_resid, const int* __restrict__ batch,
    const ushort* __restrict__ se_buf, const int* __restrict__ deg,
    const int* __restrict__ off, const float* __restrict__ agg_sum,
    const ushort* __restrict__ w_n21, const ushort* __restrict__ w_n22,
    const float* __restrict__ b_n21, const float* __restrict__ b_n22,
    float* __restrict__ x_out, float* __restrict__ n_agg, int has_resid)
{
  __shared__ __align__(16) char sA[16384];
  __shared__ __align__(16) char sB[32768];
  __shared__ __align__(16) char sH[16384];
  __shared__ int sBat[64], sDeg[64], sOff[64];
  __shared__ float sRinv[64];
  __shared__ float sNagg[NG*DD];

  const int t = threadIdx.x;
  const int wv = t >> 6, ln = t & 63, l15 = ln & 15, lhi = ln >> 4;
  const int n0 = blockIdx.x * 64;

  if (t < 64){
    int nd = n0 + t;
    int ok = nd < N_NODES;
    sBat[t] = ok ? batch[nd] : 0;
    int d = ok ? deg[nd] : 0;
    sDeg[t] = d;
    sOff[t] = ok ? off[nd] : 0;
    sRinv[t] = 1.f / fmaxf((float)d, 1.f);
  }
  for (int i = t; i < NG*DD; i += 256) sNagg[i] = 0.f;
  __syncthreads();

  float s[32];
  const int r4 = t >> 2, q = t & 3;
  if (CSR){
    #pragma unroll
    for (int k = 0; k < 32; ++k) s[k] = 0.f;
    int d = sDeg[r4], o = sOff[r4];
    for (int i = 0; i < d; ++i){
      const ushort* src = se_buf + (long)(o + i)*HH + q*32;
      #pragma unroll
      for (int c = 0; c < 4; ++c){
        uint4v v = *(const uint4v*)(src + c*8);
        #pragma unroll
        for (int jj = 0; jj < 4; ++jj){
          s[c*8 + jj*2]     += bflo(v[jj]);
          s[c*8 + jj*2 + 1] += bfhi(v[jj]);
        }
      }
    }
    float riv = sRinv[r4];
    #pragma unroll
    for (int k = 0; k < 32; ++k) s[k] *= riv;
  }

  f32x4 acc[8];
  #pragma unroll
  for (int n = 0; n < 8; ++n) acc[n] = f32x4{0.f,0.f,0.f,0.f};

  for (int half = 0; half < 2; ++half){
    if (CSR){
      for (int task = t; task < 512; task += 256){
        int r = task >> 3, c = task & 7;
        int nd = n0 + r;
        bool ok = nd < N_NODES;
        float4 lo = {0,0,0,0}, hi = {0,0,0,0};
        if (ok){
          const float* src = (half == 0) ? (x_cur + (long)nd*DD + c*8)
                                         : (u_cur + (long)sBat[r]*DD + c*8);
          lo = *(const float4*)src; hi = *(const float4*)(src + 4);
        }
        uint4v v; v.x = pk2(lo.x, lo.y); v.y = pk2(lo.z, lo.w);
        v.z = pk2(hi.x, hi.y); v.w = pk2(hi.z, hi.w);
        st_chunk(sA, r, (half == 0) ? c : (8 + c), v);
      }
      if ((half == 0 && q < 2) || (half == 1 && q >= 2)){
        int cbase = (half == 0) ? (8 + q*4) : ((q - 2)*4);
        #pragma unroll
        for (int cc = 0; cc < 4; ++cc){
          uint4v v;
          v.x = pk2(s[cc*8+0], s[cc*8+1]); v.y = pk2(s[cc*8+2], s[cc*8+3]);
          v.z = pk2(s[cc*8+4], s[cc*8+5]); v.w = pk2(s[cc*8+6], s[cc*8+7]);
          st_chunk(sA, r4, cbase + cc, v);
        }
      }
    } else {
      for (int task = t; task < 1024; task += 256){
        int r = task >> 4, c = task & 15;
        int nd = n0 + r;
        bool ok = nd < N_NODES;
        float scale = 1.f;
        const float* src;
        if (half == 0){
          if (c < 8) src = x_cur + (long)nd*DD + c*8;
          else { src = agg_sum + (long)nd*HH + (c-8)*8; scale = sRinv[r]; }
        } else {
          if (c < 8){ src = agg_sum + (long)nd*HH + 64 + c*8; scale = sRinv[r]; }
          else src = u_cur + (long)sBat[r]*DD + (c-8)*8;
        }
        float4 lo = {0,0,0,0}, hi = {0,0,0,0};
        if (ok){ lo = *(const float4*)src; hi = *(const float4*)(src + 4); }
        uint4v v; v.x = pk2(lo.x*scale, lo.y*scale); v.y = pk2(lo.z*scale, lo.w*scale);
        v.z = pk2(hi.x*scale, hi.y*scale); v.w = pk2(hi.z*scale, hi.w*scale);
        st_chunk(sA, r, c, v);
      }
    }
    stage_b(sB, w_n21, 128, 256, half*128, t, 256);
    __syncthreads();
    gemm_acc<8>(sA, sB, wv, l15, lhi, acc);
    __syncthreads();
  }
  epi_lds<8, true>(sH, acc, b_n21, wv, l15, lhi);
  stage_b(sB, w_n22, 64, 128, 0, t, 256);
  __syncthreads();

  f32x4 acc2[4];
  #pragma unroll
  for (int n = 0; n < 4; ++n) acc2[n] = f32x4{0.f,0.f,0.f,0.f};
  gemm_acc<4>(sH, sB, wv, l15, lhi, acc2);

  #pragma unroll
  for (int n = 0; n < 4; ++n){
    float bv = b_n22[n*16 + l15];
    #pragma unroll
    for (int j = 0; j < 4; ++j){
      int r = wv*16 + lhi*4 + j;
      int nd = n0 + r;
      if (nd < N_NODES){
        int col = n*16 + l15;
        float v = acc2[n][j] + bv;
        long xg = (long)nd*DD + col;
        x_out[xg] = has_resid ? (v + x_resid[xg]) : v;
        atomicAdd(&sNagg[sBat[r]*DD + col], v);
      }
    }
  }
  __syncthreads();
  for (int i = t; i < NG*DD; i += 256) atomicAdd(n_agg + i, sNagg[i]);
}

// ---------------- global (per-graph) MLP, fp32 ----------------
__global__ void global_kernel(const float* __restrict__ u_cur, const float* __restrict__ n_agg,
                              const float* __restrict__ e_agg, const float* __restrict__ cnt_b,
                              const float* __restrict__ cnt_e,
                              const float* __restrict__ g_w1, const float* __restrict__ g_b1,
                              const float* __restrict__ g_w2, const float* __restrict__ g_b2,
                              const float* __restrict__ u_resid, float* __restrict__ u_out,
                              int has_resid)
{
  int g = blockIdx.x, t = threadIdx.x;   // 192 threads
  __shared__ float uh[192];
  __shared__ float hb[128];
  float v;
  if (t < 64)       v = u_cur[g*64 + t];
  else if (t < 128) v = n_agg[g*64 + (t-64)] / fmaxf(cnt_b[g], 1.f);
  else              v = e_agg[g*64 + (t-128)] / fmaxf(cnt_e[g], 1.f);
  uh[t] = v;
  __syncthreads();
  if (t < 128){
    float s = g_b1[t];
    for (int k = 0; k < 192; ++k) s += uh[k] * g_w1[k*128 + t];
    hb[t] = fmaxf(s, 0.f);
  }
  __syncthreads();
  if (t < 64){
    float s = g_b2[t];
    for (int k = 0; k < 128; ++k) s += hb[k] * g_w2[k*64 + t];
    if (has_resid) s += u_resid[g*64 + t];
    u_out[g*64 + t] = s;
  }
}

extern "C" void kernel_launch(void* const* d_in, const int* in_sizes, int n_in,
                              void* d_out, int out_size, void* d_ws, size_t ws_size,
                              hipStream_t stream)
{
  const float* x0   = (const float*)d_in[0];
  const float* e0   = (const float*)d_in[1];
  const float* u0   = (const float*)d_in[2];
  const float* e_w1 = (const float*)d_in[3];
  const float* e_b1 = (const float*)d_in[4];
  const float* e_w2 = (const float*)d_in[5];
  const float* e_b2 = (const float*)d_in[6];
  const float* e_w3 = (const float*)d_in[7];
  const float* e_b3 = (const float*)d_in[8];
  const float* n1_w1 = (const float*)d_in[9];
  const float* n1_b1 = (const float*)d_in[10];
  const float* n1_w2 = (const float*)d_in[11];
  const float* n1_b2 = (const float*)d_in[12];
  const float* n2_w1 = (const float*)d_in[13];
  const float* n2_b1 = (const float*)d_in[14];
  const float* n2_w2 = (const float*)d_in[15];
  const float* n2_b2 = (const float*)d_in[16];
  const float* g_w1 = (const float*)d_in[17];
  const float* g_b1 = (const float*)d_in[18];
  const float* g_w2 = (const float*)d_in[19];
  const float* g_b2 = (const float*)d_in[20];
  const int* edge_index = (const int*)d_in[21];
  const int* batch      = (const int*)d_in[22];

  float* out_x = (float*)d_out;
  float* out_e = out_x + (long)N_NODES*DD;
  float* out_u = out_e + (long)E_EDGES*DD;

  char* ws = (char*)d_ws;
  int*   deg    = (int*)(ws + 0);
  int*   off    = (int*)(ws + 200000);
  int*   cursor = (int*)(ws + 400000);
  int*   bsum   = (int*)(ws + 600000);
  int*   bbase  = (int*)(ws + 600256);
  float* cnt_eb = (float*)(ws + 600512);
  float* cnt_b  = (float*)(ws + 600576);
  float* e_agg  = (float*)(ws + 600640);
  float* n_agg  = (float*)(ws + 604736);
  ushort* packed = (ushort*)(ws + 608832);   // 524,288 -> ends 1,133,120
  const size_t big = 1133120;
  bool use_csr = ws_size >= (size_t)(big + 204800000 + 3200000);
  ushort* se_buf = (ushort*)(ws + big);
  int*    pos    = (int*)(ws + big + 204800000);
  float*  agg_sum = (float*)(ws + big);      // fallback overlay

  (void)hipMemsetAsync(deg, 0, 200000, stream);
  (void)hipMemsetAsync(cnt_eb, 0, 128, stream);
  pack_weights<<<1024, 256, 0, stream>>>(e_w1, e_w2, e_w3, n1_w1, n1_w2, n2_w1, n2_w2, packed);
  hist_kernel<<<3125, 256, 0, stream>>>(edge_index, batch, deg, cnt_eb);
  count_nodes_kernel<<<196, 256, 0, stream>>>(batch, cnt_b);
  if (use_csr){
    scan_a<<<NB_SCAN, 1024, 0, stream>>>(deg, bsum);
    scan_b<<<1, 64, 0, stream>>>(bsum, bbase);
    scan_c<<<NB_SCAN, 1024, 0, stream>>>(deg, bbase, off, cursor);
    fill_kernel<<<3125, 256, 0, stream>>>(edge_index, cursor, pos);
  }

  const float* xc = x0;
  const float* ec = e0;
  const float* uc = u0;
  for (int l = 0; l < 2; ++l){
    (void)hipMemsetAsync(e_agg, 0, 8192, stream);
    if (!use_csr)
      (void)hipMemsetAsync(agg_sum, 0, (size_t)N_NODES*HH*4, stream);
    const ushort* P = packed + (long)l*131072;
    if (use_csr){
      edge_kernel<true><<<512, 512, 0, stream>>>(
          xc, ec, uc, e0, edge_index, batch, pos,
          P + 0, P + 32768, P + 49152, P + 57344, P + 73728,
          e_b1 + l*128, e_b2 + l*128, e_b3 + l*64, n1_b1 + l*128, n1_b2 + l*128,
          out_e, se_buf, agg_sum, e_agg, l == 1);
      node_kernel<true><<<782, 256, 0, stream>>>(
          xc, uc, x0, batch, se_buf, deg, off, agg_sum,
          P + 90112, P + 122880, n2_b1 + l*128, n2_b2 + l*64,
          out_x, n_agg, l == 1);
    } else {
      edge_kernel<false><<<512, 512, 0, stream>>>(
          xc, ec, uc, e0, edge_index, batch, pos,
          P + 0, P + 32768, P + 49152, P + 57344, P + 73728,
          e_b1 + l*128, e_b2 + l*128, e_b3 + l*64, n1_b1 + l*128, n1_b2 + l*128,
          out_e, se_buf, agg_sum, e_agg, l == 1);
      node_kernel<false><<<782, 256, 0, stream>>>(
          xc, uc, x0, batch, se_buf, deg, off, agg_sum,
          P + 90112, P + 122880, n2_b1 + l*128, n2_b2 + l*64,
          out_x, n_agg, l == 1);
    }
    global_kernel<<<NG, 192, 0, stream>>>(
        uc, n_agg, e_agg, cnt_b, cnt_eb,
        g_w1 + l*192*128, g_b1 + l*128, g_w2 + l*128*64, g_b2 + l*64,
        u0, out_u, l == 1);
    xc = out_x; ec = out_e; uc = out_u;
  }
}

// Round 5
// 2219.458 us; speedup vs baseline: 1.2892x; 1.1637x over previous
//
#include <hip/hip_runtime.h>

#define N_NODES 50000
#define E_EDGES 800000
#define NG 16
#define DD 64
#define HH 128
#define NB_SCAN 49
#define NTILES 12500

typedef __attribute__((ext_vector_type(8))) __bf16 bf16x8;
typedef __attribute__((ext_vector_type(4))) float f32x4;
typedef unsigned int uint;
typedef unsigned short ushort;
typedef __attribute__((ext_vector_type(4))) uint uint4v;

#define MFMA16(a,b,c) __builtin_amdgcn_mfma_f32_16x16x32_bf16((a),(b),(c),0,0,0)

__device__ __forceinline__ ushort f2bf(float f){
  uint u = __builtin_bit_cast(uint, f);
  u += 0x7fffu + ((u >> 16) & 1u);
  return (ushort)(u >> 16);
}
__device__ __forceinline__ uint pk2(float a, float b){
  return (uint)f2bf(a) | ((uint)f2bf(b) << 16);
}
__device__ __forceinline__ float bflo(uint u){ return __builtin_bit_cast(float, u << 16); }
__device__ __forceinline__ float bfhi(uint u){ return __builtin_bit_cast(float, u & 0xffff0000u); }

// barrier that does NOT drain vmcnt: LDS-visibility only.
__device__ __forceinline__ void lds_barrier(){
  asm volatile("s_waitcnt lgkmcnt(0)" ::: "memory");
  __builtin_amdgcn_s_barrier();
}

// ---- pitch-256B LDS helpers, XOR-swizzled 16B chunks ----
__device__ __forceinline__ bf16x8 ldfrag(const char* base, int row, int byteoff){
  uint4v v = *(const uint4v*)(base + row*256 + (byteoff ^ ((row & 7) << 4)));
  return __builtin_bit_cast(bf16x8, v);
}
__device__ __forceinline__ uint4v ld_chunk(const char* base, int row, int c16){
  return *(const uint4v*)(base + row*256 + ((c16*16) ^ ((row & 7) << 4)));
}
__device__ __forceinline__ void st_h(char* base, int row, int col, float v){
  *(ushort*)(base + row*256 + ((col*2) ^ ((row & 7) << 4))) = f2bf(v);
}
__device__ __forceinline__ void st_chunk(char* base, int row, int c16, uint4v v){
  *(uint4v*)(base + row*256 + ((c16*16) ^ ((row & 7) << 4))) = v;
}
__device__ __forceinline__ void pack16(char* dst, int r, int c16, const float* src){
  float4 lo = *(const float4*)src;
  float4 hi = *(const float4*)(src + 4);
  uint4v v; v.x = pk2(lo.x, lo.y); v.y = pk2(lo.z, lo.w);
  v.z = pk2(hi.x, hi.y); v.w = pk2(hi.z, hi.w);
  st_chunk(dst, r, c16, v);
}

// node-kernel helpers (4 waves)
__device__ __forceinline__ void stage_b(char* sB, const ushort* wt,
                                        int Nout, int Ktot, int koff, int t, int stride){
  for (int task = t; task < Nout*16; task += stride){
    int n = task >> 4, c = task & 15;
    uint4v v = *(const uint4v*)(wt + (long)n*Ktot + koff + c*8);
    st_chunk(sB, n, c, v);
  }
}
template<int NT>
__device__ __forceinline__ void gemm_acc(const char* A, const char* B,
                                         int wv, int l15, int lhi, f32x4* acc){
  #pragma unroll
  for (int kt = 0; kt < 4; ++kt){
    bf16x8 a = ldfrag(A, wv*16 + l15, kt*64 + lhi*16);
    #pragma unroll
    for (int n = 0; n < NT; ++n){
      bf16x8 bb = ldfrag(B, n*16 + l15, kt*64 + lhi*16);
      acc[n] = MFMA16(a, bb, acc[n]);
    }
  }
}
template<int NT, bool RELU>
__device__ __forceinline__ void epi_lds(char* dst, const f32x4* acc, const float* bias,
                                        int wv, int l15, int lhi){
  #pragma unroll
  for (int n = 0; n < NT; ++n){
    float bv = bias[n*16 + l15];
    #pragma unroll
    for (int j = 0; j < 4; ++j){
      int r = wv*16 + lhi*4 + j;
      float v = acc[n][j] + bv;
      if (RELU) v = fmaxf(v, 0.f);
      st_h(dst, r, n*16 + l15, v);
    }
  }
}

// ---------------- weight pack: fp32 [L][K][N] -> bf16 transposed [L][N][K] ----------
__global__ void pack_weights(const float* __restrict__ e1, const float* __restrict__ e2,
                             const float* __restrict__ e3, const float* __restrict__ n11,
                             const float* __restrict__ n12, const float* __restrict__ n21,
                             const float* __restrict__ n22, ushort* __restrict__ out){
  int idx = blockIdx.x * 256 + threadIdx.x;
  int l = idx / 131072, r = idx % 131072;
  const float* src; int K, N, off;
  if      (r <  32768){ src = e1;  K = 256; N = 128; off = 0; }
  else if (r <  49152){ src = e2;  K = 128; N = 128; off = 32768; }
  else if (r <  57344){ src = e3;  K = 128; N = 64;  off = 49152; }
  else if (r <  73728){ src = n11; K = 128; N = 128; off = 57344; }
  else if (r <  90112){ src = n12; K = 128; N = 128; off = 73728; }
  else if (r < 122880){ src = n21; K = 256; N = 128; off = 90112; }
  else                { src = n22; K = 128; N = 64;  off = 122880; }
  int q = r - off; int k = q / N; int n = q % N;
  out[(long)l*131072 + off + n*K + k] = f2bf(src[(long)l*K*N + q]);
}

// ---------------- counts / CSR ----------------
__global__ void hist_kernel(const int* __restrict__ edge_index, const int* __restrict__ batch,
                            int* __restrict__ deg, float* __restrict__ cnt_eb){
  __shared__ float h[NG];
  int t = threadIdx.x;
  if (t < NG) h[t] = 0.f;
  __syncthreads();
  int e = blockIdx.x * 256 + t;
  if (e < E_EDGES){
    atomicAdd(deg + edge_index[E_EDGES + e], 1);
    atomicAdd(&h[batch[edge_index[e]]], 1.f);
  }
  __syncthreads();
  if (t < NG) atomicAdd(cnt_eb + t, h[t]);
}
__global__ void count_nodes_kernel(const int* __restrict__ batch, float* __restrict__ cnt_b){
  __shared__ float h[NG];
  int t = threadIdx.x;
  if (t < NG) h[t] = 0.f;
  __syncthreads();
  int n = blockIdx.x * 256 + t;
  if (n < N_NODES) atomicAdd(&h[batch[n]], 1.f);
  __syncthreads();
  if (t < NG) atomicAdd(cnt_b + t, h[t]);
}
__global__ void scan_a(const int* __restrict__ deg, int* __restrict__ bsum){
  __shared__ int red[1024];
  int i = blockIdx.x*1024 + threadIdx.x;
  red[threadIdx.x] = (i < N_NODES) ? deg[i] : 0;
  __syncthreads();
  for (int s = 512; s > 0; s >>= 1){
    if ((int)threadIdx.x < s) red[threadIdx.x] += red[threadIdx.x + s];
    __syncthreads();
  }
  if (threadIdx.x == 0) bsum[blockIdx.x] = red[0];
}
__global__ void scan_b(const int* __restrict__ bsum, int* __restrict__ bbase){
  if (threadIdx.x == 0){
    int run = 0;
    for (int b = 0; b < NB_SCAN; ++b){ int v = bsum[b]; bbase[b] = run; run += v; }
  }
}
__global__ void scan_c(const int* __restrict__ deg, const int* __restrict__ bbase,
                       int* __restrict__ off, int* __restrict__ cursor){
  __shared__ int sc[1024];
  int i = blockIdx.x*1024 + threadIdx.x;
  int v = (i < N_NODES) ? deg[i] : 0;
  sc[threadIdx.x] = v;
  __syncthreads();
  for (int d = 1; d < 1024; d <<= 1){
    int add = ((int)threadIdx.x >= d) ? sc[threadIdx.x - d] : 0;
    __syncthreads();
    sc[threadIdx.x] += add;
    __syncthreads();
  }
  if (i < N_NODES){
    int ex = sc[threadIdx.x] - v + bbase[blockIdx.x];
    off[i] = ex; cursor[i] = ex;
  }
}
__global__ void fill_kernel(const int* __restrict__ edge_index, int* __restrict__ cursor,
                            int* __restrict__ pos){
  int e = blockIdx.x*256 + threadIdx.x;
  if (e < E_EDGES){
    int c = edge_index[E_EDGES + e];
    pos[e] = atomicAdd(&cursor[c], 1);
  }
}

// ============ edge kernel v5: persistent blocks, pipelined gathers, lgkm-only barriers =====
// 8 waves: mw = wv&1 (rows mw*32..+31, 2 m-frags), ng = wv>>1 (cols ng*32..+31, 2 n-frags)
// per-thread gather identity: cc = t&31 (chunk column), rr = t>>5; rows it*16+rr, it=0..3
template<bool CSR>
__global__ __launch_bounds__(512, 2) void edge_kernel(
    const float* __restrict__ x_cur, const float* __restrict__ e_cur,
    const float* __restrict__ u_cur, const float* __restrict__ e_resid,
    const int* __restrict__ edge_index, const int* __restrict__ batch,
    const int* __restrict__ pos_arr,
    const ushort* __restrict__ w_e1, const ushort* __restrict__ w_e2,
    const ushort* __restrict__ w_e3, const ushort* __restrict__ w_n11,
    const ushort* __restrict__ w_n12,
    const float* __restrict__ b_e1, const float* __restrict__ b_e2,
    const float* __restrict__ b_e3, const float* __restrict__ b_n11,
    const float* __restrict__ b_n12,
    float* __restrict__ e_out, ushort* __restrict__ se_buf,
    float* __restrict__ agg_sum, float* __restrict__ e_agg, int has_resid)
{
  __shared__ __align__(16) char sA[16384];   // 64 x 128 bf16, pitch 256
  __shared__ __align__(16) char sH[16384];   // 64 x 128 bf16, pitch 256
  __shared__ __align__(16) char sB[32768];   // weight tile 128 x 128 bf16
  __shared__ float sEagg[NG*DD];
  __shared__ int sRow[2][64], sCol[2][64], sEb[2][64];

  const int t = threadIdx.x;
  const int wv = t >> 6, ln = t & 63, l15 = ln & 15, lhi = ln >> 4;
  const int mw = wv & 1, ng = wv >> 1;
  const int cc = t & 31, rr = t >> 5;

  // persistent e_w3 B-fragments (16 VGPR)
  bf16x8 b3[4];
  #pragma unroll
  for (int kt = 0; kt < 4; ++kt)
    b3[kt] = *(const bf16x8*)(w_e3 + (long)(ng*16 + l15)*128 + kt*32 + lhi*8);

  for (int i = t; i < NG*DD; i += 512) sEagg[i] = 0.f;

  uint4v wA[4];      // weight stage in flight
  float4 raw[8];     // gather in flight (fp32)
  uint4v gk[4];      // packed bf16 gather for current tile

  auto LOADW = [&](const ushort* W, int K, int KOFF){
    #pragma unroll
    for (int it = 0; it < 4; ++it)
      wA[it] = *(const uint4v*)(W + (long)(it*32 + (t >> 4))*K + KOFF + (t & 15)*8);
  };
  auto STOREW = [&](){
    #pragma unroll
    for (int it = 0; it < 4; ++it)
      st_chunk(sB, it*32 + (t >> 4), t & 15, wA[it]);
  };
  auto GATHER = [&](int base, int p, bool doU, bool doRest){
    #pragma unroll
    for (int it = 0; it < 4; ++it){
      int r = it*16 + rr;
      const float* s;
      bool go;
      if (cc < 8)      { s = x_cur + (long)sRow[p][r]*DD + cc*8;          go = doRest; }
      else if (cc < 16){ s = x_cur + (long)sCol[p][r]*DD + (cc-8)*8;      go = doRest; }
      else if (cc < 24){ s = e_cur + (long)(base + r)*DD + (cc-16)*8;     go = doRest; }
      else             { s = u_cur + (long)sEb[p][r]*DD + (cc-24)*8;      go = doU;   }
      if (go){ raw[2*it] = *(const float4*)s; raw[2*it+1] = *(const float4*)(s + 4); }
    }
  };
  auto PACK = [&](){
    #pragma unroll
    for (int it = 0; it < 4; ++it){
      uint4v v;
      v.x = pk2(raw[2*it].x, raw[2*it].y);   v.y = pk2(raw[2*it].z, raw[2*it].w);
      v.z = pk2(raw[2*it+1].x, raw[2*it+1].y); v.w = pk2(raw[2*it+1].z, raw[2*it+1].w);
      gk[it] = v;
    }
  };
  f32x4 acc[2][2];
  auto ZACC = [&](){
    #pragma unroll
    for (int m = 0; m < 2; ++m){ acc[m][0] = f32x4{0,0,0,0}; acc[m][1] = f32x4{0,0,0,0}; }
  };
  auto GEMMP = [&](const char* base){
    #pragma unroll
    for (int kt = 0; kt < 4; ++kt){
      bf16x8 a0 = ldfrag(base, mw*32 + l15,      kt*64 + lhi*16);
      bf16x8 a1 = ldfrag(base, mw*32 + 16 + l15, kt*64 + lhi*16);
      bf16x8 bb0 = ldfrag(sB, (ng*2    )*16 + l15, kt*64 + lhi*16);
      bf16x8 bb1 = ldfrag(sB, (ng*2 + 1)*16 + l15, kt*64 + lhi*16);
      acc[0][0] = MFMA16(a0, bb0, acc[0][0]);
      acc[0][1] = MFMA16(a0, bb1, acc[0][1]);
      acc[1][0] = MFMA16(a1, bb0, acc[1][0]);
      acc[1][1] = MFMA16(a1, bb1, acc[1][1]);
    }
  };
  auto EPI = [&](char* dst, const float* bias, bool relu){
    #pragma unroll
    for (int m = 0; m < 2; ++m)
      #pragma unroll
      for (int n = 0; n < 2; ++n){
        int col = ng*32 + n*16 + l15;
        float bv = bias[col];
        #pragma unroll
        for (int j = 0; j < 4; ++j){
          float v = acc[m][n][j] + bv;
          if (relu) v = fmaxf(v, 0.f);
          st_h(dst, mw*32 + m*16 + lhi*4 + j, col, v);
        }
      }
  };

  // ---------------- prologue: tile0 indices, gathers, e_w1h0 ----------------
  int tile = blockIdx.x;
  int par = 0;
  if (t < 64){
    int r0 = edge_index[tile*64 + t];
    sRow[0][t] = r0; sCol[0][t] = edge_index[E_EDGES + tile*64 + t];
    sEb[0][t] = batch[r0];
  }
  LOADW(w_e1, 256, 0);
  __syncthreads();
  GATHER(tile*64, 0, true, true);
  STOREW();                 // sB <- e_w1 h0
  PACK();
  lds_barrier();

  for (; tile < NTILES; tile += gridDim.x){
    const int ebase = tile*64;
    const int nt = tile + gridDim.x;
    const bool hn = nt < NTILES;
    const int q = par ^ 1;

    // P0: sA <- kh0 (x_row|x_col); issue e_w1 h1
    if (cc < 16){
      #pragma unroll
      for (int it = 0; it < 4; ++it) st_chunk(sA, it*16 + rr, cc, gk[it]);
    }
    LOADW(w_e1, 256, 128);
    lds_barrier();

    // P1: GEMM1a; issue next-tile index loads
    ZACC();
    GEMMP(sA);
    int iR = 0, iC = 0;
    if (hn && t < 64){
      iR = edge_index[nt*64 + t];
      iC = edge_index[E_EDGES + nt*64 + t];
    }
    lds_barrier();

    // P2: sA <- kh1 (e|u); sB <- e_w1 h1
    if (cc >= 16){
      #pragma unroll
      for (int it = 0; it < 4; ++it) st_chunk(sA, it*16 + rr, cc - 16, gk[it]);
    }
    STOREW();
    lds_barrier();

    // P3: GEMM1b + epi->sH; issue e_w2; store next idx, issue batch
    GEMMP(sA);
    EPI(sH, b_e1, true);
    LOADW(w_e2, 128, 0);
    int iB = 0;
    if (hn && t < 64){
      sRow[q][t] = iR; sCol[q][t] = iC;
      iB = batch[iR];
    }
    lds_barrier();

    // P4: sB <- e_w2
    STOREW();
    lds_barrier();

    // P5: GEMM2 (A=sH) epi->sA (H2); issue n1_w1; store sEb[q]
    ZACC();
    GEMMP(sH);
    EPI(sA, b_e2, true);
    LOADW(w_n11, 128, 0);
    if (hn && t < 64) sEb[q][t] = iB;
    lds_barrier();

    // P6: GEMM3 (A=sA H2, B=b3 regs) -> e_out/sEagg/sH(c64-127); x_row regs -> sH(c0-63); sB <- n1_w1
    {
      f32x4 a3[2];
      a3[0] = f32x4{0,0,0,0}; a3[1] = f32x4{0,0,0,0};
      #pragma unroll
      for (int kt = 0; kt < 4; ++kt){
        bf16x8 a0 = ldfrag(sA, mw*32 + l15,      kt*64 + lhi*16);
        bf16x8 a1 = ldfrag(sA, mw*32 + 16 + l15, kt*64 + lhi*16);
        a3[0] = MFMA16(a0, b3[kt], a3[0]);
        a3[1] = MFMA16(a1, b3[kt], a3[1]);
      }
      int col = ng*16 + l15;
      float bv = b_e3[col];
      #pragma unroll
      for (int m = 0; m < 2; ++m)
        #pragma unroll
        for (int j = 0; j < 4; ++j){
          int r = mw*32 + m*16 + lhi*4 + j;
          float v = a3[m][j] + bv;
          long eg = (long)(ebase + r)*DD + col;
          e_out[eg] = has_resid ? (v + e_resid[eg]) : v;
          atomicAdd(&sEagg[sEb[par][r]*DD + col], v);
          st_h(sH, r, 64 + col, v);
        }
      if (cc < 8){
        #pragma unroll
        for (int it = 0; it < 4; ++it) st_chunk(sH, it*16 + rr, cc, gk[it]);
      }
      STOREW();
    }
    lds_barrier();

    // P7: GEMM4 (A=sH [x|e_new]) epi->sA (H3); issue n1_w2; issue next gathers (x/e)
    ZACC();
    GEMMP(sH);
    EPI(sA, b_n11, true);
    LOADW(w_n12, 128, 0);
    if (hn) GATHER(nt*64, q, false, true);
    lds_barrier();

    // P8: sB <- n1_w2; issue next u gathers
    STOREW();
    if (hn) GATHER(nt*64, q, true, false);
    lds_barrier();

    // P9: GEMM5 (A=sA H3); issue next e_w1 h0
    ZACC();
    GEMMP(sA);
    if (CSR){
      EPI(sH, b_n12, false);
    } else {
      #pragma unroll
      for (int m = 0; m < 2; ++m)
        #pragma unroll
        for (int n = 0; n < 2; ++n){
          int col = ng*32 + n*16 + l15;
          float bv = b_n12[col];
          #pragma unroll
          for (int j = 0; j < 4; ++j)
            atomicAdd(agg_sum + (long)sCol[par][mw*32 + m*16 + lhi*4 + j]*HH + col,
                      acc[m][n][j] + bv);
        }
    }
    if (hn) LOADW(w_e1, 256, 0);
    lds_barrier();

    // P10: scatter SE; pack next gathers; sB <- e_w1 h0
    if (CSR){
      int r = t >> 3, oct = t & 7;
      long p = pos_arr[ebase + r];
      uint4v v0 = ld_chunk(sH, r, oct*2);
      uint4v v1 = ld_chunk(sH, r, oct*2 + 1);
      *(uint4v*)(se_buf + p*128 + oct*16) = v0;
      *(uint4v*)(se_buf + p*128 + oct*16 + 8) = v1;
    }
    if (hn){ STOREW(); PACK(); }
    par = q;
    lds_barrier();
  }

  __syncthreads();
  for (int i = t; i < NG*DD; i += 512) atomicAdd(e_agg + i, sEagg[i]);
}

// ---------------- node kernel: mean-gather + node-MLP2 (R2 version) ----------------
template<bool CSR>
__global__ __launch_bounds__(256, 2) void node_kernel(
    const float* __restrict__ x_cur, const float* __restrict__ u_cur,
    const float* __restrict__ x_resid, const int* __restrict__ batch,
    const ushort* __restrict__ se_buf, const int* __restrict__ deg,
    const int* __restrict__ off, const float* __restrict__ agg_sum,
    const ushort* __restrict__ w_n21, const ushort* __restrict__ w_n22,
    const float* __restrict__ b_n21, const float* __restrict__ b_n22,
    float* __restrict__ x_out, float* __restrict__ n_agg, int has_resid)
{
  __shared__ __align__(16) char sA[16384];
  __shared__ __align__(16) char sB[32768];
  __shared__ __align__(16) char sH[16384];
  __shared__ int sBat[64], sDeg[64], sOff[64];
  __shared__ float sRinv[64];
  __shared__ float sNagg[NG*DD];

  const int t = threadIdx.x;
  const int wv = t >> 6, ln = t & 63, l15 = ln & 15, lhi = ln >> 4;
  const int n0 = blockIdx.x * 64;

  if (t < 64){
    int nd = n0 + t;
    int ok = nd < N_NODES;
    sBat[t] = ok ? batch[nd] : 0;
    int d = ok ? deg[nd] : 0;
    sDeg[t] = d;
    sOff[t] = ok ? off[nd] : 0;
    sRinv[t] = 1.f / fmaxf((float)d, 1.f);
  }
  for (int i = t; i < NG*DD; i += 256) sNagg[i] = 0.f;
  __syncthreads();

  float s[32];
  const int r4 = t >> 2, q = t & 3;
  if (CSR){
    #pragma unroll
    for (int k = 0; k < 32; ++k) s[k] = 0.f;
    int d = sDeg[r4], o = sOff[r4];
    for (int i = 0; i < d; ++i){
      const ushort* src = se_buf + (long)(o + i)*HH + q*32;
      #pragma unroll
      for (int c = 0; c < 4; ++c){
        uint4v v = *(const uint4v*)(src + c*8);
        #pragma unroll
        for (int jj = 0; jj < 4; ++jj){
          s[c*8 + jj*2]     += bflo(v[jj]);
          s[c*8 + jj*2 + 1] += bfhi(v[jj]);
        }
      }
    }
    float riv = sRinv[r4];
    #pragma unroll
    for (int k = 0; k < 32; ++k) s[k] *= riv;
  }

  f32x4 acc[8];
  #pragma unroll
  for (int n = 0; n < 8; ++n) acc[n] = f32x4{0.f,0.f,0.f,0.f};

  for (int half = 0; half < 2; ++half){
    if (CSR){
      for (int task = t; task < 512; task += 256){
        int r = task >> 3, c = task & 7;
        int nd = n0 + r;
        bool ok = nd < N_NODES;
        float4 lo = {0,0,0,0}, hi = {0,0,0,0};
        if (ok){
          const float* src = (half == 0) ? (x_cur + (long)nd*DD + c*8)
                                         : (u_cur + (long)sBat[r]*DD + c*8);
          lo = *(const float4*)src; hi = *(const float4*)(src + 4);
        }
        uint4v v; v.x = pk2(lo.x, lo.y); v.y = pk2(lo.z, lo.w);
        v.z = pk2(hi.x, hi.y); v.w = pk2(hi.z, hi.w);
        st_chunk(sA, r, (half == 0) ? c : (8 + c), v);
      }
      if ((half == 0 && q < 2) || (half == 1 && q >= 2)){
        int cbase = (half == 0) ? (8 + q*4) : ((q - 2)*4);
        #pragma unroll
        for (int ccv = 0; ccv < 4; ++ccv){
          uint4v v;
          v.x = pk2(s[ccv*8+0], s[ccv*8+1]); v.y = pk2(s[ccv*8+2], s[ccv*8+3]);
          v.z = pk2(s[ccv*8+4], s[ccv*8+5]); v.w = pk2(s[ccv*8+6], s[ccv*8+7]);
          st_chunk(sA, r4, cbase + ccv, v);
        }
      }
    } else {
      for (int task = t; task < 1024; task += 256){
        int r = task >> 4, c = task & 15;
        int nd = n0 + r;
        bool ok = nd < N_NODES;
        float scale = 1.f;
        const float* src;
        if (half == 0){
          if (c < 8) src = x_cur + (long)nd*DD + c*8;
          else { src = agg_sum + (long)nd*HH + (c-8)*8; scale = sRinv[r]; }
        } else {
          if (c < 8){ src = agg_sum + (long)nd*HH + 64 + c*8; scale = sRinv[r]; }
          else src = u_cur + (long)sBat[r]*DD + (c-8)*8;
        }
        float4 lo = {0,0,0,0}, hi = {0,0,0,0};
        if (ok){ lo = *(const float4*)src; hi = *(const float4*)(src + 4); }
        uint4v v; v.x = pk2(lo.x*scale, lo.y*scale); v.y = pk2(lo.z*scale, lo.w*scale);
        v.z = pk2(hi.x*scale, hi.y*scale); v.w = pk2(hi.z*scale, hi.w*scale);
        st_chunk(sA, r, c, v);
      }
    }
    stage_b(sB, w_n21, 128, 256, half*128, t, 256);
    __syncthreads();
    gemm_acc<8>(sA, sB, wv, l15, lhi, acc);
    __syncthreads();
  }
  epi_lds<8, true>(sH, acc, b_n21, wv, l15, lhi);
  stage_b(sB, w_n22, 64, 128, 0, t, 256);
  __syncthreads();

  f32x4 acc2[4];
  #pragma unroll
  for (int n = 0; n < 4; ++n) acc2[n] = f32x4{0.f,0.f,0.f,0.f};
  gemm_acc<4>(sH, sB, wv, l15, lhi, acc2);

  #pragma unroll
  for (int n = 0; n < 4; ++n){
    float bv = b_n22[n*16 + l15];
    #pragma unroll
    for (int j = 0; j < 4; ++j){
      int r = wv*16 + lhi*4 + j;
      int nd = n0 + r;
      if (nd < N_NODES){
        int col = n*16 + l15;
        float v = acc2[n][j] + bv;
        long xg = (long)nd*DD + col;
        x_out[xg] = has_resid ? (v + x_resid[xg]) : v;
        atomicAdd(&sNagg[sBat[r]*DD + col], v);
      }
    }
  }
  __syncthreads();
  for (int i = t; i < NG*DD; i += 256) atomicAdd(n_agg + i, sNagg[i]);
}

// ---------------- global (per-graph) MLP, fp32 ----------------
__global__ void global_kernel(const float* __restrict__ u_cur, const float* __restrict__ n_agg,
                              const float* __restrict__ e_agg, const float* __restrict__ cnt_b,
                              const float* __restrict__ cnt_e,
                              const float* __restrict__ g_w1, const float* __restrict__ g_b1,
                              const float* __restrict__ g_w2, const float* __restrict__ g_b2,
                              const float* __restrict__ u_resid, float* __restrict__ u_out,
                              int has_resid)
{
  int g = blockIdx.x, t = threadIdx.x;   // 192 threads
  __shared__ float uh[192];
  __shared__ float hb[128];
  float v;
  if (t < 64)       v = u_cur[g*64 + t];
  else if (t < 128) v = n_agg[g*64 + (t-64)] / fmaxf(cnt_b[g], 1.f);
  else              v = e_agg[g*64 + (t-128)] / fmaxf(cnt_e[g], 1.f);
  uh[t] = v;
  __syncthreads();
  if (t < 128){
    float s = g_b1[t];
    for (int k = 0; k < 192; ++k) s += uh[k] * g_w1[k*128 + t];
    hb[t] = fmaxf(s, 0.f);
  }
  __syncthreads();
  if (t < 64){
    float s = g_b2[t];
    for (int k = 0; k < 128; ++k) s += hb[k] * g_w2[k*64 + t];
    if (has_resid) s += u_resid[g*64 + t];
    u_out[g*64 + t] = s;
  }
}

extern "C" void kernel_launch(void* const* d_in, const int* in_sizes, int n_in,
                              void* d_out, int out_size, void* d_ws, size_t ws_size,
                              hipStream_t stream)
{
  const float* x0   = (const float*)d_in[0];
  const float* e0   = (const float*)d_in[1];
  const float* u0   = (const float*)d_in[2];
  const float* e_w1 = (const float*)d_in[3];
  const float* e_b1 = (const float*)d_in[4];
  const float* e_w2 = (const float*)d_in[5];
  const float* e_b2 = (const float*)d_in[6];
  const float* e_w3 = (const float*)d_in[7];
  const float* e_b3 = (const float*)d_in[8];
  const float* n1_w1 = (const float*)d_in[9];
  const float* n1_b1 = (const float*)d_in[10];
  const float* n1_w2 = (const float*)d_in[11];
  const float* n1_b2 = (const float*)d_in[12];
  const float* n2_w1 = (const float*)d_in[13];
  const float* n2_b1 = (const float*)d_in[14];
  const float* n2_w2 = (const float*)d_in[15];
  const float* n2_b2 = (const float*)d_in[16];
  const float* g_w1 = (const float*)d_in[17];
  const float* g_b1 = (const float*)d_in[18];
  const float* g_w2 = (const float*)d_in[19];
  const float* g_b2 = (const float*)d_in[20];
  const int* edge_index = (const int*)d_in[21];
  const int* batch      = (const int*)d_in[22];

  float* out_x = (float*)d_out;
  float* out_e = out_x + (long)N_NODES*DD;
  float* out_u = out_e + (long)E_EDGES*DD;

  char* ws = (char*)d_ws;
  int*   deg    = (int*)(ws + 0);
  int*   off    = (int*)(ws + 200000);
  int*   cursor = (int*)(ws + 400000);
  int*   bsum   = (int*)(ws + 600000);
  int*   bbase  = (int*)(ws + 600256);
  float* cnt_eb = (float*)(ws + 600512);
  float* cnt_b  = (float*)(ws + 600576);
  float* e_agg  = (float*)(ws + 600640);
  float* n_agg  = (float*)(ws + 604736);
  ushort* packed = (ushort*)(ws + 608832);   // 524,288 -> ends 1,133,120
  const size_t big = 1133120;
  bool use_csr = ws_size >= (size_t)(big + 204800000 + 3200000);
  ushort* se_buf = (ushort*)(ws + big);
  int*    pos    = (int*)(ws + big + 204800000);
  float*  agg_sum = (float*)(ws + big);      // fallback overlay

  (void)hipMemsetAsync(deg, 0, 200000, stream);
  (void)hipMemsetAsync(cnt_eb, 0, 128, stream);
  pack_weights<<<1024, 256, 0, stream>>>(e_w1, e_w2, e_w3, n1_w1, n1_w2, n2_w1, n2_w2, packed);
  hist_kernel<<<3125, 256, 0, stream>>>(edge_index, batch, deg, cnt_eb);
  count_nodes_kernel<<<196, 256, 0, stream>>>(batch, cnt_b);
  if (use_csr){
    scan_a<<<NB_SCAN, 1024, 0, stream>>>(deg, bsum);
    scan_b<<<1, 64, 0, stream>>>(bsum, bbase);
    scan_c<<<NB_SCAN, 1024, 0, stream>>>(deg, bbase, off, cursor);
    fill_kernel<<<3125, 256, 0, stream>>>(edge_index, cursor, pos);
  }

  const float* xc = x0;
  const float* ec = e0;
  const float* uc = u0;
  for (int l = 0; l < 2; ++l){
    (void)hipMemsetAsync(e_agg, 0, 8192, stream);
    if (!use_csr)
      (void)hipMemsetAsync(agg_sum, 0, (size_t)N_NODES*HH*4, stream);
    const ushort* P = packed + (long)l*131072;
    if (use_csr){
      edge_kernel<true><<<512, 512, 0, stream>>>(
          xc, ec, uc, e0, edge_index, batch, pos,
          P + 0, P + 32768, P + 49152, P + 57344, P + 73728,
          e_b1 + l*128, e_b2 + l*128, e_b3 + l*64, n1_b1 + l*128, n1_b2 + l*128,
          out_e, se_buf, agg_sum, e_agg, l == 1);
      node_kernel<true><<<782, 256, 0, stream>>>(
          xc, uc, x0, batch, se_buf, deg, off, agg_sum,
          P + 90112, P + 122880, n2_b1 + l*128, n2_b2 + l*64,
          out_x, n_agg, l == 1);
    } else {
      edge_kernel<false><<<512, 512, 0, stream>>>(
          xc, ec, uc, e0, edge_index, batch, pos,
          P + 0, P + 32768, P + 49152, P + 57344, P + 73728,
          e_b1 + l*128, e_b2 + l*128, e_b3 + l*64, n1_b1 + l*128, n1_b2 + l*128,
          out_e, se_buf, agg_sum, e_agg, l == 1);
      node_kernel<false><<<782, 256, 0, stream>>>(
          xc, uc, x0, batch, se_buf, deg, off, agg_sum,
          P + 90112, P + 122880, n2_b1 + l*128, n2_b2 + l*64,
          out_x, n_agg, l == 1);
    }
    global_kernel<<<NG, 192, 0, stream>>>(
        uc, n_agg, e_agg, cnt_b, cnt_eb,
        g_w1 + l*192*128, g_b1 + l*128, g_w2 + l*128*64, g_b2 + l*64,
        u0, out_u, l == 1);
    xc = out_x; ec = out_e; uc = out_u;
  }
}

// Round 6
// 1910.428 us; speedup vs baseline: 1.4977x; 1.1618x over previous
//
#include <hip/hip_runtime.h>

#define N_NODES 50000
#define E_EDGES 800000
#define NG 16
#define DD 64
#define HH 128
#define NB_SCAN 49

typedef __attribute__((ext_vector_type(8))) __bf16 bf16x8;
typedef __attribute__((ext_vector_type(4))) float f32x4;
typedef unsigned int uint;
typedef unsigned short ushort;
typedef __attribute__((ext_vector_type(4))) uint uint4v;

#define MFMA16(a,b,c) __builtin_amdgcn_mfma_f32_16x16x32_bf16((a),(b),(c),0,0,0)

__device__ __forceinline__ ushort f2bf(float f){
  uint u = __builtin_bit_cast(uint, f);
  u += 0x7fffu + ((u >> 16) & 1u);
  return (ushort)(u >> 16);
}
__device__ __forceinline__ uint pk2(float a, float b){
  return (uint)f2bf(a) | ((uint)f2bf(b) << 16);
}
__device__ __forceinline__ float bflo(uint u){ return __builtin_bit_cast(float, u << 16); }
__device__ __forceinline__ float bfhi(uint u){ return __builtin_bit_cast(float, u & 0xffff0000u); }

// ---- pitch-256B LDS helpers (swizzled 16B chunks) ----
__device__ __forceinline__ bf16x8 ldfrag(const char* base, int row, int byteoff){
  uint4v v = *(const uint4v*)(base + row*256 + (byteoff ^ ((row & 7) << 4)));
  return __builtin_bit_cast(bf16x8, v);
}
__device__ __forceinline__ uint4v ld_chunk(const char* base, int row, int c16){
  return *(const uint4v*)(base + row*256 + ((c16*16) ^ ((row & 7) << 4)));
}
__device__ __forceinline__ void st_h(char* base, int row, int col, float v){
  *(ushort*)(base + row*256 + ((col*2) ^ ((row & 7) << 4))) = f2bf(v);
}
__device__ __forceinline__ void st_chunk(char* base, int row, int c16, uint4v v){
  *(uint4v*)(base + row*256 + ((c16*16) ^ ((row & 7) << 4))) = v;
}
// ---- pitch-128B LDS helpers (for 64-col K-chunk tiles) ----
__device__ __forceinline__ bf16x8 ldfrag128(const char* base, int row, int byteoff){
  uint4v v = *(const uint4v*)(base + row*128 + (byteoff ^ ((row & 7) << 4)));
  return __builtin_bit_cast(bf16x8, v);
}
__device__ __forceinline__ void st_chunk128(char* base, int row, int c16, uint4v v){
  *(uint4v*)(base + row*128 + ((c16*16) ^ ((row & 7) << 4))) = v;
}
__device__ __forceinline__ void pack16_128(char* dst, int r, int c16, const float* src){
  float4 lo = *(const float4*)src;
  float4 hi = *(const float4*)(src + 4);
  uint4v v; v.x = pk2(lo.x, lo.y); v.y = pk2(lo.z, lo.w);
  v.z = pk2(hi.x, hi.y); v.w = pk2(hi.z, hi.w);
  st_chunk128(dst, r, c16, v);
}

// node-kernel helpers (4 waves) — R2-proven
__device__ __forceinline__ void stage_b(char* sB, const ushort* wt,
                                        int Nout, int Ktot, int koff, int t, int stride){
  for (int task = t; task < Nout*16; task += stride){
    int n = task >> 4, c = task & 15;
    uint4v v = *(const uint4v*)(wt + (long)n*Ktot + koff + c*8);
    st_chunk(sB, n, c, v);
  }
}
__device__ __forceinline__ void pack16(char* dst, int r, int c16, const float* src){
  float4 lo = *(const float4*)src;
  float4 hi = *(const float4*)(src + 4);
  uint4v v; v.x = pk2(lo.x, lo.y); v.y = pk2(lo.z, lo.w);
  v.z = pk2(hi.x, hi.y); v.w = pk2(hi.z, hi.w);
  st_chunk(dst, r, c16, v);
}
template<int NT>
__device__ __forceinline__ void gemm_acc(const char* A, const char* B,
                                         int wv, int l15, int lhi, f32x4* acc){
  #pragma unroll
  for (int kt = 0; kt < 4; ++kt){
    bf16x8 a = ldfrag(A, wv*16 + l15, kt*64 + lhi*16);
    #pragma unroll
    for (int n = 0; n < NT; ++n){
      bf16x8 bb = ldfrag(B, n*16 + l15, kt*64 + lhi*16);
      acc[n] = MFMA16(a, bb, acc[n]);
    }
  }
}
template<int NT, bool RELU>
__device__ __forceinline__ void epi_lds(char* dst, const f32x4* acc, const float* bias,
                                        int wv, int l15, int lhi){
  #pragma unroll
  for (int n = 0; n < NT; ++n){
    float bv = bias[n*16 + l15];
    #pragma unroll
    for (int j = 0; j < 4; ++j){
      int r = wv*16 + lhi*4 + j;
      float v = acc[n][j] + bv;
      if (RELU) v = fmaxf(v, 0.f);
      st_h(dst, r, n*16 + l15, v);
    }
  }
}

// ---------------- weight pack: fp32 [L][K][N] -> bf16 transposed [N][K] ----------
// per-layer layout (ushort): e_w1t@0(32768) e_w2t@32768(16384) e_w3t@49152(8192)
//  n1_w2t@57344(16384) n2_w1t@73728(32768) n2_w2t@106496(8192) wct@114688(24576) -> 139264
__global__ void pack_weights(const float* __restrict__ e1, const float* __restrict__ e2,
                             const float* __restrict__ e3, const float* __restrict__ n12,
                             const float* __restrict__ n21, const float* __restrict__ n22,
                             ushort* __restrict__ out){
  int idx = blockIdx.x * 256 + threadIdx.x;   // 2*114688
  int l = idx / 114688, r = idx % 114688;
  const float* src; int K, N, off;
  if      (r <  32768){ src = e1;  K = 256; N = 128; off = 0; }
  else if (r <  49152){ src = e2;  K = 128; N = 128; off = 32768; }
  else if (r <  57344){ src = e3;  K = 128; N = 64;  off = 49152; }
  else if (r <  73728){ src = n12; K = 128; N = 128; off = 57344; }
  else if (r < 106496){ src = n21; K = 256; N = 128; off = 73728; }
  else                { src = n22; K = 128; N = 64;  off = 106496; }
  int q = r - off; int k = q / N; int n = q % N;
  out[(long)l*139264 + off + n*K + k] = f2bf(src[(long)l*K*N + q]);
}

// fused weight Wc[n][k], k<64: n1_w1[k][n]; k>=64: sum_m e_w3[k-64][m]*n1_w1[64+m][n]
__global__ void make_wc(const float* __restrict__ n1w1, const float* __restrict__ ew3,
                        const float* __restrict__ n1b1, const float* __restrict__ eb3,
                        ushort* __restrict__ packed, float* __restrict__ biasc){
  int l = blockIdx.x, t = threadIdx.x;
  const float* W1 = n1w1 + (long)l*128*128;   // [K=128][N=128]
  const float* W3 = ew3 + (long)l*128*64;     // [K=128][M=64]
  ushort* wc = packed + (long)l*139264 + 114688;  // [N=128][K=192]
  for (int i = t; i < 8192; i += 256){
    int k = i >> 7, n = i & 127;
    wc[n*192 + k] = f2bf(W1[k*128 + n]);
  }
  for (int i = t; i < 16384; i += 256){
    int k2 = i >> 7, n = i & 127;
    float s = 0.f;
    for (int m = 0; m < 64; ++m) s += W3[k2*64 + m] * W1[(64 + m)*128 + n];
    wc[n*192 + 64 + k2] = f2bf(s);
  }
  if (t < 128){
    float s = n1b1[l*128 + t];
    for (int m = 0; m < 64; ++m) s += eb3[l*64 + m] * W1[(64 + m)*128 + t];
    biasc[l*128 + t] = s;
  }
}

// ---------------- counts / CSR ----------------
__global__ void hist_kernel(const int* __restrict__ edge_index, const int* __restrict__ batch,
                            int* __restrict__ deg, float* __restrict__ cnt_eb){
  __shared__ float h[NG];
  int t = threadIdx.x;
  if (t < NG) h[t] = 0.f;
  __syncthreads();
  int e = blockIdx.x * 256 + t;
  if (e < E_EDGES){
    atomicAdd(deg + edge_index[E_EDGES + e], 1);
    atomicAdd(&h[batch[edge_index[e]]], 1.f);
  }
  __syncthreads();
  if (t < NG) atomicAdd(cnt_eb + t, h[t]);
}
__global__ void count_nodes_kernel(const int* __restrict__ batch, float* __restrict__ cnt_b){
  __shared__ float h[NG];
  int t = threadIdx.x;
  if (t < NG) h[t] = 0.f;
  __syncthreads();
  int n = blockIdx.x * 256 + t;
  if (n < N_NODES) atomicAdd(&h[batch[n]], 1.f);
  __syncthreads();
  if (t < NG) atomicAdd(cnt_b + t, h[t]);
}
__global__ void scan_a(const int* __restrict__ deg, int* __restrict__ bsum){
  __shared__ int red[1024];
  int i = blockIdx.x*1024 + threadIdx.x;
  red[threadIdx.x] = (i < N_NODES) ? deg[i] : 0;
  __syncthreads();
  for (int s = 512; s > 0; s >>= 1){
    if ((int)threadIdx.x < s) red[threadIdx.x] += red[threadIdx.x + s];
    __syncthreads();
  }
  if (threadIdx.x == 0) bsum[blockIdx.x] = red[0];
}
__global__ void scan_b(const int* __restrict__ bsum, int* __restrict__ bbase){
  if (threadIdx.x == 0){
    int run = 0;
    for (int b = 0; b < NB_SCAN; ++b){ int v = bsum[b]; bbase[b] = run; run += v; }
  }
}
__global__ void scan_c(const int* __restrict__ deg, const int* __restrict__ bbase,
                       int* __restrict__ off, int* __restrict__ cursor){
  __shared__ int sc[1024];
  int i = blockIdx.x*1024 + threadIdx.x;
  int v = (i < N_NODES) ? deg[i] : 0;
  sc[threadIdx.x] = v;
  __syncthreads();
  for (int d = 1; d < 1024; d <<= 1){
    int add = ((int)threadIdx.x >= d) ? sc[threadIdx.x - d] : 0;
    __syncthreads();
    sc[threadIdx.x] += add;
    __syncthreads();
  }
  if (i < N_NODES){
    int ex = sc[threadIdx.x] - v + bbase[blockIdx.x];
    off[i] = ex; cursor[i] = ex;
  }
}
__global__ void fill_kernel(const int* __restrict__ edge_index, int* __restrict__ cursor,
                            int* __restrict__ pos){
  int e = blockIdx.x*256 + threadIdx.x;
  if (e < E_EDGES){
    int c = edge_index[E_EDGES + e];
    pos[e] = atomicAdd(&cursor[c], 1);
  }
}

// ============ K123: gather -> GEMM1 (K=256) -> GEMM2 -> H2 (stored in out_e region) =====
// 4 waves; wave wv owns rows wv*32..+31 (2 m-frags), all 128 cols (8 n-frags).
// LDS: A@0 (16K, pitch128), B@16K (16K, pitch128), OV=H tile @16K..48K (pitch256).
__global__ __launch_bounds__(256, 3) void k123_kernel(
    const float* __restrict__ x_cur, const float* e_cur,
    const float* __restrict__ u_cur,
    const int* __restrict__ ei, const int* __restrict__ batch,
    const ushort* __restrict__ w1t, const ushort* __restrict__ w2t,
    const float* __restrict__ be1, const float* __restrict__ be2,
    ushort* h2g)
{
  __shared__ __align__(16) char lds[49152];
  __shared__ int sRow[128], sCol[128], sEb[128];
  char* A  = lds;
  char* B  = lds + 16384;
  char* OV = lds + 16384;
  const int t = threadIdx.x;
  const int wv = t >> 6, l15 = t & 15, lhi = (t >> 4) & 3;
  const int ebase = blockIdx.x * 128;

  if (t < 128){
    int r = ei[ebase + t];
    sRow[t] = r; sCol[t] = ei[E_EDGES + ebase + t]; sEb[t] = batch[r];
  }
  __syncthreads();

  f32x4 acc[2][8];
  #pragma unroll
  for (int m = 0; m < 2; ++m)
    #pragma unroll
    for (int n = 0; n < 8; ++n) acc[m][n] = f32x4{0,0,0,0};

  // GEMM1: 4 K-chunks (x_row | x_col | e | u)
  for (int c = 0; c < 4; ++c){
    #pragma unroll
    for (int it = 0; it < 4; ++it){
      int task = t + it*256, r = task >> 3, c16 = task & 7;
      const float* s;
      if      (c == 0) s = x_cur + (long)sRow[r]*DD + c16*8;
      else if (c == 1) s = x_cur + (long)sCol[r]*DD + c16*8;
      else if (c == 2) s = e_cur + (long)(ebase + r)*DD + c16*8;
      else             s = u_cur + (long)sEb[r]*DD + c16*8;
      pack16_128(A, r, c16, s);
    }
    #pragma unroll
    for (int it = 0; it < 4; ++it){
      int task = t + it*256, n = task >> 3, c16 = task & 7;
      st_chunk128(B, n, c16, *(const uint4v*)(w1t + (long)n*256 + c*64 + c16*8));
    }
    __syncthreads();
    #pragma unroll
    for (int kt = 0; kt < 2; ++kt){
      bf16x8 a0 = ldfrag128(A, wv*32 + l15,      kt*64 + lhi*16);
      bf16x8 a1 = ldfrag128(A, wv*32 + 16 + l15, kt*64 + lhi*16);
      #pragma unroll
      for (int n = 0; n < 8; ++n){
        bf16x8 bb = ldfrag128(B, n*16 + l15, kt*64 + lhi*16);
        acc[0][n] = MFMA16(a0, bb, acc[0][n]);
        acc[1][n] = MFMA16(a1, bb, acc[1][n]);
      }
    }
    __syncthreads();
  }
  // epi H1 -> OV
  #pragma unroll
  for (int m = 0; m < 2; ++m)
    #pragma unroll
    for (int n = 0; n < 8; ++n){
      int col = n*16 + l15;
      float bv = be1[col];
      #pragma unroll
      for (int j = 0; j < 4; ++j)
        st_h(OV, wv*32 + m*16 + lhi*4 + j, col, fmaxf(acc[m][n][j] + bv, 0.f));
    }
  __syncthreads();

  // GEMM2: K=128 in 2 chunks, B staged into A region, A-operand = OV (H1)
  #pragma unroll
  for (int m = 0; m < 2; ++m)
    #pragma unroll
    for (int n = 0; n < 8; ++n) acc[m][n] = f32x4{0,0,0,0};
  for (int kc = 0; kc < 2; ++kc){
    #pragma unroll
    for (int it = 0; it < 4; ++it){
      int task = t + it*256, n = task >> 3, c16 = task & 7;
      st_chunk128(A, n, c16, *(const uint4v*)(w2t + (long)n*128 + kc*64 + c16*8));
    }
    __syncthreads();
    #pragma unroll
    for (int kt = 0; kt < 2; ++kt){
      bf16x8 a0 = ldfrag(OV, wv*32 + l15,      kc*128 + kt*64 + lhi*16);
      bf16x8 a1 = ldfrag(OV, wv*32 + 16 + l15, kc*128 + kt*64 + lhi*16);
      #pragma unroll
      for (int n = 0; n < 8; ++n){
        bf16x8 bb = ldfrag128(A, n*16 + l15, kt*64 + lhi*16);
        acc[0][n] = MFMA16(a0, bb, acc[0][n]);
        acc[1][n] = MFMA16(a1, bb, acc[1][n]);
      }
    }
    __syncthreads();
  }
  // epi H2 -> OV (H1 dead), then coalesced write to h2g (the out_e region)
  #pragma unroll
  for (int m = 0; m < 2; ++m)
    #pragma unroll
    for (int n = 0; n < 8; ++n){
      int col = n*16 + l15;
      float bv = be2[col];
      #pragma unroll
      for (int j = 0; j < 4; ++j)
        st_h(OV, wv*32 + m*16 + lhi*4 + j, col, fmaxf(acc[m][n][j] + bv, 0.f));
    }
  __syncthreads();
  #pragma unroll
  for (int it = 0; it < 8; ++it){
    int task = t + it*256, r = task >> 4, c16 = task & 15;
    *(uint4v*)(h2g + (long)(ebase + r)*HH + c16*8) = ld_chunk(OV, r, c16);
  }
}

// ============ K45: [x|H2] GEMM4' (Wc, K=192) + GEMM3 (e_new) + GEMM5 -> SE scatter ======
// LDS: A@0 (16K p128), B@16K (16K p128), B2@32K (16K p256, 64 rows), OV=@16K..48K (p256)
template<bool CSR>
__global__ __launch_bounds__(256, 3) void k45_kernel(
    const float* __restrict__ x_cur, const ushort* h2g,
    const int* __restrict__ ei, const int* __restrict__ batch,
    const int* __restrict__ pos_arr,
    const ushort* __restrict__ w3t, const ushort* __restrict__ wct,
    const ushort* __restrict__ w5t,
    const float* __restrict__ be3, const float* __restrict__ biasc,
    const float* __restrict__ bn12,
    float* e_outf, const float* __restrict__ e_resid,
    ushort* __restrict__ se_buf, float* __restrict__ agg_sum,
    float* __restrict__ e_agg, int has_resid)
{
  __shared__ __align__(16) char lds[49152];
  __shared__ float sEagg[NG*DD];
  __shared__ int sIdx[128];
  char* A  = lds;
  char* B  = lds + 16384;
  char* B2 = lds + 32768;
  char* OV = lds + 16384;
  const int t = threadIdx.x;
  const int wv = t >> 6, l15 = t & 15, lhi = (t >> 4) & 3;
  const int ebase = blockIdx.x * 128;

  if (t < 128) sIdx[t] = ei[ebase + t];    // src row for x gather
  for (int i = t; i < NG*DD; i += 256) sEagg[i] = 0.f;
  __syncthreads();

  f32x4 acc4[2][8], acc3[2][4];
  #pragma unroll
  for (int m = 0; m < 2; ++m){
    #pragma unroll
    for (int n = 0; n < 8; ++n) acc4[m][n] = f32x4{0,0,0,0};
    #pragma unroll
    for (int n = 0; n < 4; ++n) acc3[m][n] = f32x4{0,0,0,0};
  }

  for (int c = 0; c < 3; ++c){
    if (c == 0){
      #pragma unroll
      for (int it = 0; it < 4; ++it){
        int task = t + it*256, r = task >> 3, c16 = task & 7;
        pack16_128(A, r, c16, x_cur + (long)sIdx[r]*DD + c16*8);
      }
      #pragma unroll
      for (int it = 0; it < 4; ++it){         // B2 <- e_w3t [64][128]
        int task = t + it*256, n = task >> 4, c16 = task & 15;
        st_chunk(B2, n, c16, *(const uint4v*)(w3t + (long)n*128 + c16*8));
      }
    } else {
      #pragma unroll
      for (int it = 0; it < 4; ++it){
        int task = t + it*256, r = task >> 3, c16 = task & 7;
        st_chunk128(A, r, c16,
            *(const uint4v*)(h2g + (long)(ebase + r)*HH + (c-1)*64 + c16*8));
      }
    }
    #pragma unroll
    for (int it = 0; it < 4; ++it){
      int task = t + it*256, n = task >> 3, c16 = task & 7;
      st_chunk128(B, n, c16, *(const uint4v*)(wct + (long)n*192 + c*64 + c16*8));
    }
    __syncthreads();
    #pragma unroll
    for (int kt = 0; kt < 2; ++kt){
      bf16x8 a0 = ldfrag128(A, wv*32 + l15,      kt*64 + lhi*16);
      bf16x8 a1 = ldfrag128(A, wv*32 + 16 + l15, kt*64 + lhi*16);
      #pragma unroll
      for (int n = 0; n < 8; ++n){
        bf16x8 bb = ldfrag128(B, n*16 + l15, kt*64 + lhi*16);
        acc4[0][n] = MFMA16(a0, bb, acc4[0][n]);
        acc4[1][n] = MFMA16(a1, bb, acc4[1][n]);
      }
      if (c >= 1){
        #pragma unroll
        for (int n = 0; n < 4; ++n){
          bf16x8 b2 = ldfrag(B2, n*16 + l15, (c-1)*128 + kt*64 + lhi*16);
          acc3[0][n] = MFMA16(a0, b2, acc3[0][n]);
          acc3[1][n] = MFMA16(a1, b2, acc3[1][n]);
        }
      }
    }
    __syncthreads();
  }

  // epi: e_out (overwrites own H2 rows) + e_agg partials; H3 -> OV; stage G5-B kc0 -> A
  #pragma unroll
  for (int m = 0; m < 2; ++m)
    #pragma unroll
    for (int n = 0; n < 4; ++n){
      int col = n*16 + l15;
      float bv = be3[col];
      #pragma unroll
      for (int j = 0; j < 4; ++j){
        int row = wv*32 + m*16 + lhi*4 + j;
        float v = acc3[m][n][j] + bv;
        long eg = (long)(ebase + row)*DD + col;
        e_outf[eg] = has_resid ? (v + e_resid[eg]) : v;
        int eb = batch[ei[ebase + row]];
        atomicAdd(&sEagg[eb*DD + col], v);
      }
    }
  #pragma unroll
  for (int m = 0; m < 2; ++m)
    #pragma unroll
    for (int n = 0; n < 8; ++n){
      int col = n*16 + l15;
      float bv = biasc[col];
      #pragma unroll
      for (int j = 0; j < 4; ++j)
        st_h(OV, wv*32 + m*16 + lhi*4 + j, col, fmaxf(acc4[m][n][j] + bv, 0.f));
    }
  #pragma unroll
  for (int it = 0; it < 4; ++it){
    int task = t + it*256, n = task >> 3, c16 = task & 7;
    st_chunk128(A, n, c16, *(const uint4v*)(w5t + (long)n*128 + c16*8));
  }
  if (t < 128) sIdx[t] = CSR ? pos_arr[ebase + t] : ei[E_EDGES + ebase + t];
  __syncthreads();

  // GEMM5: K=128 in 2 chunks (B in A region), A-operand = OV (H3)
  f32x4 acc5[2][8];
  #pragma unroll
  for (int m = 0; m < 2; ++m)
    #pragma unroll
    for (int n = 0; n < 8; ++n) acc5[m][n] = f32x4{0,0,0,0};
  #pragma unroll
  for (int kt = 0; kt < 2; ++kt){
    bf16x8 a0 = ldfrag(OV, wv*32 + l15,      kt*64 + lhi*16);
    bf16x8 a1 = ldfrag(OV, wv*32 + 16 + l15, kt*64 + lhi*16);
    #pragma unroll
    for (int n = 0; n < 8; ++n){
      bf16x8 bb = ldfrag128(A, n*16 + l15, kt*64 + lhi*16);
      acc5[0][n] = MFMA16(a0, bb, acc5[0][n]);
      acc5[1][n] = MFMA16(a1, bb, acc5[1][n]);
    }
  }
  __syncthreads();
  #pragma unroll
  for (int it = 0; it < 4; ++it){
    int task = t + it*256, n = task >> 3, c16 = task & 7;
    st_chunk128(A, n, c16, *(const uint4v*)(w5t + (long)n*128 + 64 + c16*8));
  }
  __syncthreads();
  #pragma unroll
  for (int kt = 0; kt < 2; ++kt){
    bf16x8 a0 = ldfrag(OV, wv*32 + l15,      128 + kt*64 + lhi*16);
    bf16x8 a1 = ldfrag(OV, wv*32 + 16 + l15, 128 + kt*64 + lhi*16);
    #pragma unroll
    for (int n = 0; n < 8; ++n){
      bf16x8 bb = ldfrag128(A, n*16 + l15, kt*64 + lhi*16);
      acc5[0][n] = MFMA16(a0, bb, acc5[0][n]);
      acc5[1][n] = MFMA16(a1, bb, acc5[1][n]);
    }
  }
  __syncthreads();

  if (CSR){
    // SE epi -> OV (H3 dead), then coalesced scatter by pos
    #pragma unroll
    for (int m = 0; m < 2; ++m)
      #pragma unroll
      for (int n = 0; n < 8; ++n){
        int col = n*16 + l15;
        float bv = bn12[col];
        #pragma unroll
        for (int j = 0; j < 4; ++j)
          st_h(OV, wv*32 + m*16 + lhi*4 + j, col, acc5[m][n][j] + bv);
      }
    __syncthreads();
    #pragma unroll
    for (int it = 0; it < 8; ++it){
      int task = t + it*256, r = task >> 4, c16 = task & 15;
      *(uint4v*)(se_buf + (long)sIdx[r]*HH + c16*8) = ld_chunk(OV, r, c16);
    }
  } else {
    #pragma unroll
    for (int m = 0; m < 2; ++m)
      #pragma unroll
      for (int n = 0; n < 8; ++n){
        int col = n*16 + l15;
        float bv = bn12[col];
        #pragma unroll
        for (int j = 0; j < 4; ++j){
          int row = wv*32 + m*16 + lhi*4 + j;
          atomicAdd(agg_sum + (long)sIdx[row]*HH + col, acc5[m][n][j] + bv);
        }
      }
    __syncthreads();
  }
  for (int i = t; i < NG*DD; i += 256) atomicAdd(e_agg + i, sEagg[i]);
}

// ---------------- node kernel: mean-gather + node-MLP2 (R2-proven) ----------------
template<bool CSR>
__global__ __launch_bounds__(256, 2) void node_kernel(
    const float* __restrict__ x_cur, const float* __restrict__ u_cur,
    const float* __restrict__ x_resid, const int* __restrict__ batch,
    const ushort* __restrict__ se_buf, const int* __restrict__ deg,
    const int* __restrict__ off, const float* __restrict__ agg_sum,
    const ushort* __restrict__ w_n21, const ushort* __restrict__ w_n22,
    const float* __restrict__ b_n21, const float* __restrict__ b_n22,
    float* __restrict__ x_out, float* __restrict__ n_agg, int has_resid)
{
  __shared__ __align__(16) char sA[16384];
  __shared__ __align__(16) char sB[32768];
  __shared__ __align__(16) char sH[16384];
  __shared__ int sBat[64], sDeg[64], sOff[64];
  __shared__ float sRinv[64];
  __shared__ float sNagg[NG*DD];

  const int t = threadIdx.x;
  const int wv = t >> 6, ln = t & 63, l15 = ln & 15, lhi = ln >> 4;
  const int n0 = blockIdx.x * 64;

  if (t < 64){
    int nd = n0 + t;
    int ok = nd < N_NODES;
    sBat[t] = ok ? batch[nd] : 0;
    int d = ok ? deg[nd] : 0;
    sDeg[t] = d;
    sOff[t] = ok ? off[nd] : 0;
    sRinv[t] = 1.f / fmaxf((float)d, 1.f);
  }
  for (int i = t; i < NG*DD; i += 256) sNagg[i] = 0.f;
  __syncthreads();

  float s[32];
  const int r4 = t >> 2, q = t & 3;
  if (CSR){
    #pragma unroll
    for (int k = 0; k < 32; ++k) s[k] = 0.f;
    int d = sDeg[r4], o = sOff[r4];
    for (int i = 0; i < d; ++i){
      const ushort* src = se_buf + (long)(o + i)*HH + q*32;
      #pragma unroll
      for (int c = 0; c < 4; ++c){
        uint4v v = *(const uint4v*)(src + c*8);
        #pragma unroll
        for (int jj = 0; jj < 4; ++jj){
          s[c*8 + jj*2]     += bflo(v[jj]);
          s[c*8 + jj*2 + 1] += bfhi(v[jj]);
        }
      }
    }
    float riv = sRinv[r4];
    #pragma unroll
    for (int k = 0; k < 32; ++k) s[k] *= riv;
  }

  f32x4 acc[8];
  #pragma unroll
  for (int n = 0; n < 8; ++n) acc[n] = f32x4{0.f,0.f,0.f,0.f};

  for (int half = 0; half < 2; ++half){
    if (CSR){
      for (int task = t; task < 512; task += 256){
        int r = task >> 3, c = task & 7;
        int nd = n0 + r;
        bool ok = nd < N_NODES;
        float4 lo = {0,0,0,0}, hi = {0,0,0,0};
        if (ok){
          const float* src = (half == 0) ? (x_cur + (long)nd*DD + c*8)
                                         : (u_cur + (long)sBat[r]*DD + c*8);
          lo = *(const float4*)src; hi = *(const float4*)(src + 4);
        }
        uint4v v; v.x = pk2(lo.x, lo.y); v.y = pk2(lo.z, lo.w);
        v.z = pk2(hi.x, hi.y); v.w = pk2(hi.z, hi.w);
        st_chunk(sA, r, (half == 0) ? c : (8 + c), v);
      }
      if ((half == 0 && q < 2) || (half == 1 && q >= 2)){
        int cbase = (half == 0) ? (8 + q*4) : ((q - 2)*4);
        #pragma unroll
        for (int cc = 0; cc < 4; ++cc){
          uint4v v;
          v.x = pk2(s[cc*8+0], s[cc*8+1]); v.y = pk2(s[cc*8+2], s[cc*8+3]);
          v.z = pk2(s[cc*8+4], s[cc*8+5]); v.w = pk2(s[cc*8+6], s[cc*8+7]);
          st_chunk(sA, r4, cbase + cc, v);
        }
      }
    } else {
      for (int task = t; task < 1024; task += 256){
        int r = task >> 4, c = task & 15;
        int nd = n0 + r;
        bool ok = nd < N_NODES;
        float scale = 1.f;
        const float* src;
        if (half == 0){
          if (c < 8) src = x_cur + (long)nd*DD + c*8;
          else { src = agg_sum + (long)nd*HH + (c-8)*8; scale = sRinv[r]; }
        } else {
          if (c < 8){ src = agg_sum + (long)nd*HH + 64 + c*8; scale = sRinv[r]; }
          else src = u_cur + (long)sBat[r]*DD + (c-8)*8;
        }
        float4 lo = {0,0,0,0}, hi = {0,0,0,0};
        if (ok){ lo = *(const float4*)src; hi = *(const float4*)(src + 4); }
        uint4v v; v.x = pk2(lo.x*scale, lo.y*scale); v.y = pk2(lo.z*scale, lo.w*scale);
        v.z = pk2(hi.x*scale, hi.y*scale); v.w = pk2(hi.z*scale, hi.w*scale);
        st_chunk(sA, r, c, v);
      }
    }
    stage_b(sB, w_n21, 128, 256, half*128, t, 256);
    __syncthreads();
    gemm_acc<8>(sA, sB, wv, l15, lhi, acc);
    __syncthreads();
  }
  epi_lds<8, true>(sH, acc, b_n21, wv, l15, lhi);
  stage_b(sB, w_n22, 64, 128, 0, t, 256);
  __syncthreads();

  f32x4 acc2[4];
  #pragma unroll
  for (int n = 0; n < 4; ++n) acc2[n] = f32x4{0.f,0.f,0.f,0.f};
  gemm_acc<4>(sH, sB, wv, l15, lhi, acc2);

  #pragma unroll
  for (int n = 0; n < 4; ++n){
    float bv = b_n22[n*16 + l15];
    #pragma unroll
    for (int j = 0; j < 4; ++j){
      int r = wv*16 + lhi*4 + j;
      int nd = n0 + r;
      if (nd < N_NODES){
        int col = n*16 + l15;
        float v = acc2[n][j] + bv;
        long xg = (long)nd*DD + col;
        x_out[xg] = has_resid ? (v + x_resid[xg]) : v;
        atomicAdd(&sNagg[sBat[r]*DD + col], v);
      }
    }
  }
  __syncthreads();
  for (int i = t; i < NG*DD; i += 256) atomicAdd(n_agg + i, sNagg[i]);
}

// ---------------- global (per-graph) MLP, fp32 ----------------
__global__ void global_kernel(const float* __restrict__ u_cur, const float* __restrict__ n_agg,
                              const float* __restrict__ e_agg, const float* __restrict__ cnt_b,
                              const float* __restrict__ cnt_e,
                              const float* __restrict__ g_w1, const float* __restrict__ g_b1,
                              const float* __restrict__ g_w2, const float* __restrict__ g_b2,
                              const float* __restrict__ u_resid, float* __restrict__ u_out,
                              int has_resid)
{
  int g = blockIdx.x, t = threadIdx.x;   // 192 threads
  __shared__ float uh[192];
  __shared__ float hb[128];
  float v;
  if (t < 64)       v = u_cur[g*64 + t];
  else if (t < 128) v = n_agg[g*64 + (t-64)] / fmaxf(cnt_b[g], 1.f);
  else              v = e_agg[g*64 + (t-128)] / fmaxf(cnt_e[g], 1.f);
  uh[t] = v;
  __syncthreads();
  if (t < 128){
    float s = g_b1[t];
    for (int k = 0; k < 192; ++k) s += uh[k] * g_w1[k*128 + t];
    hb[t] = fmaxf(s, 0.f);
  }
  __syncthreads();
  if (t < 64){
    float s = g_b2[t];
    for (int k = 0; k < 128; ++k) s += hb[k] * g_w2[k*64 + t];
    if (has_resid) s += u_resid[g*64 + t];
    u_out[g*64 + t] = s;
  }
}

extern "C" void kernel_launch(void* const* d_in, const int* in_sizes, int n_in,
                              void* d_out, int out_size, void* d_ws, size_t ws_size,
                              hipStream_t stream)
{
  const float* x0   = (const float*)d_in[0];
  const float* e0   = (const float*)d_in[1];
  const float* u0   = (const float*)d_in[2];
  const float* e_w1 = (const float*)d_in[3];
  const float* e_b1 = (const float*)d_in[4];
  const float* e_w2 = (const float*)d_in[5];
  const float* e_b2 = (const float*)d_in[6];
  const float* e_w3 = (const float*)d_in[7];
  const float* e_b3 = (const float*)d_in[8];
  const float* n1_w1 = (const float*)d_in[9];
  const float* n1_b1 = (const float*)d_in[10];
  const float* n1_w2 = (const float*)d_in[11];
  const float* n1_b2 = (const float*)d_in[12];
  const float* n2_w1 = (const float*)d_in[13];
  const float* n2_b1 = (const float*)d_in[14];
  const float* n2_w2 = (const float*)d_in[15];
  const float* n2_b2 = (const float*)d_in[16];
  const float* g_w1 = (const float*)d_in[17];
  const float* g_b1 = (const float*)d_in[18];
  const float* g_w2 = (const float*)d_in[19];
  const float* g_b2 = (const float*)d_in[20];
  const int* edge_index = (const int*)d_in[21];
  const int* batch      = (const int*)d_in[22];

  float* out_x = (float*)d_out;
  float* out_e = out_x + (long)N_NODES*DD;
  float* out_u = out_e + (long)E_EDGES*DD;

  char* ws = (char*)d_ws;
  int*   deg    = (int*)(ws + 0);
  int*   off    = (int*)(ws + 200000);
  int*   cursor = (int*)(ws + 400000);
  int*   bsum   = (int*)(ws + 600000);
  int*   bbase  = (int*)(ws + 600256);
  float* cnt_eb = (float*)(ws + 600512);
  float* cnt_b  = (float*)(ws + 600576);
  float* e_agg  = (float*)(ws + 600640);
  float* n_agg  = (float*)(ws + 604736);
  float* biascf = (float*)(ws + 608832);        // 1024 B
  ushort* packed = (ushort*)(ws + 609856);      // 2*139264*2 = 557056 -> ends 1,166,912
  const size_t big = 1166912;
  bool use_csr = ws_size >= (size_t)(big + 204800000 + 3200000);
  ushort* se_buf = (ushort*)(ws + big);
  int*    pos    = (int*)(ws + big + 204800000);
  float*  agg_sum = (float*)(ws + big);         // fallback overlay (25.6 MB)

  (void)hipMemsetAsync(deg, 0, 200000, stream);
  (void)hipMemsetAsync(cnt_eb, 0, 128, stream);
  pack_weights<<<896, 256, 0, stream>>>(e_w1, e_w2, e_w3, n1_w2, n2_w1, n2_w2, packed);
  make_wc<<<2, 256, 0, stream>>>(n1_w1, e_w3, n1_b1, e_b3, packed, biascf);
  hist_kernel<<<3125, 256, 0, stream>>>(edge_index, batch, deg, cnt_eb);
  count_nodes_kernel<<<196, 256, 0, stream>>>(batch, cnt_b);
  if (use_csr){
    scan_a<<<NB_SCAN, 1024, 0, stream>>>(deg, bsum);
    scan_b<<<1, 64, 0, stream>>>(bsum, bbase);
    scan_c<<<NB_SCAN, 1024, 0, stream>>>(deg, bbase, off, cursor);
    fill_kernel<<<3125, 256, 0, stream>>>(edge_index, cursor, pos);
  }

  const float* xc = x0;
  const float* ec = e0;
  const float* uc = u0;
  for (int l = 0; l < 2; ++l){
    (void)hipMemsetAsync(e_agg, 0, 8192, stream);   // e_agg + n_agg
    if (!use_csr)
      (void)hipMemsetAsync(agg_sum, 0, (size_t)N_NODES*HH*4, stream);
    const ushort* P = packed + (long)l*139264;
    k123_kernel<<<6250, 256, 0, stream>>>(
        xc, ec, uc, edge_index, batch,
        P + 0, P + 32768, e_b1 + l*128, e_b2 + l*128,
        (ushort*)out_e);
    if (use_csr){
      k45_kernel<true><<<6250, 256, 0, stream>>>(
          xc, (const ushort*)out_e, edge_index, batch, pos,
          P + 49152, P + 114688, P + 57344,
          e_b3 + l*64, biascf + l*128, n1_b2 + l*128,
          out_e, e0, se_buf, agg_sum, e_agg, l == 1);
      node_kernel<true><<<782, 256, 0, stream>>>(
          xc, uc, x0, batch, se_buf, deg, off, agg_sum,
          P + 73728, P + 106496, n2_b1 + l*128, n2_b2 + l*64,
          out_x, n_agg, l == 1);
    } else {
      k45_kernel<false><<<6250, 256, 0, stream>>>(
          xc, (const ushort*)out_e, edge_index, batch, pos,
          P + 49152, P + 114688, P + 57344,
          e_b3 + l*64, biascf + l*128, n1_b2 + l*128,
          out_e, e0, se_buf, agg_sum, e_agg, l == 1);
      node_kernel<false><<<782, 256, 0, stream>>>(
          xc, uc, x0, batch, se_buf, deg, off, agg_sum,
          P + 73728, P + 106496, n2_b1 + l*128, n2_b2 + l*64,
          out_x, n_agg, l == 1);
    }
    global_kernel<<<NG, 192, 0, stream>>>(
        uc, n_agg, e_agg, cnt_b, cnt_eb,
        g_w1 + l*192*128, g_b1 + l*128, g_w2 + l*128*64, g_b2 + l*64,
        u0, out_u, l == 1);
    xc = out_x; ec = out_e; uc = out_u;
  }
}